// Round 2
// baseline (401.545 us; speedup 1.0000x reference)
//
#include <hip/hip_runtime.h>
#include <cstdint>
#include <cstddef>

typedef unsigned long long u64;
typedef unsigned short u16;
typedef __bf16 bf16x8 __attribute__((ext_vector_type(8)));
typedef float f32x4 __attribute__((ext_vector_type(4)));

#define NN 4096
#define HIDD 256

// ---------- helpers ----------
__device__ __forceinline__ u16 f2bf(float f) {
  unsigned int u = __float_as_uint(f);
  u = u + 0x7FFFu + ((u >> 16) & 1u);   // RNE
  return (u16)(u >> 16);
}
__device__ __forceinline__ float bf2f(u16 h) {
  return __uint_as_float(((unsigned int)h) << 16);
}
__device__ __forceinline__ float gelu_f(float x) {
  return 0.5f * x * (1.0f + erff(x * 0.70710678118654752f));
}
__device__ __forceinline__ void gload_lds16(const u16* g, u16* l) {
  __builtin_amdgcn_global_load_lds((const __attribute__((address_space(1))) void*)g,
                                   (__attribute__((address_space(3))) void*)l, 16, 0, 0);
}

// ---------- K0: adjacency -> bitset rows (wave per row, ballot) ----------
__global__ __launch_bounds__(256) void k_bitset(const float* __restrict__ A, u64* __restrict__ B1) {
  int wv = threadIdx.x >> 6, ln = threadIdx.x & 63;
  int row = blockIdx.x * 4 + wv;
  const float* ar = A + (size_t)row * NN;
  for (int w = 0; w < 64; ++w) {
    float v = ar[w * 64 + ln];
    u64 m = __ballot(v != 0.0f);
    if (ln == 0) B1[(size_t)row * 64 + w] = m;
  }
}

// ---------- K5: boolean mat-power expansion (wave per row) ----------
__global__ __launch_bounds__(256) void k_expand(const u64* __restrict__ src,
                                                const u64* __restrict__ base,
                                                u64* __restrict__ dst) {
  int wv = threadIdx.x >> 6, ln = threadIdx.x & 63;
  int row = blockIdx.x * 4 + wv;
  u64 acc = 0;
  for (int w = 0; w < 64; ++w) {
    u64 word = src[(size_t)row * 64 + w];   // uniform across lanes
    while (word) {
      int b = __builtin_ctzll(word);
      word &= word - 1;
      int m = w * 64 + b;
      acc |= base[(size_t)m * 64 + ln];     // coalesced 512B
    }
  }
  dst[(size_t)row * 64 + ln] = acc;
}

// ---------- split f32 [R,256] -> bf16 [R,768] hi/lo concat ----------
// pat=1 (A-operand): (hi, lo, hi);  pat=0 (B-operand): (hi, hi, lo)
__global__ __launch_bounds__(256) void k_split(const float* __restrict__ src,
                                               u16* __restrict__ dst, int pat) {
  int rrow = blockIdx.x, c = threadIdx.x;
  float x = src[(size_t)rrow * 256 + c];
  u16 hi = f2bf(x);
  u16 lo = f2bf(x - bf2f(hi));
  size_t b = (size_t)rrow * 768 + c;
  dst[b] = hi;
  dst[b + 256] = pat ? lo : hi;
  dst[b + 512] = pat ? hi : lo;
}

// ---------- transpose+split weight [256,256] -> [256,768] (B-pattern) ----------
__global__ __launch_bounds__(256) void k_splitT(const float* __restrict__ W,
                                                u16* __restrict__ dst) {
  int n = blockIdx.x, k = threadIdx.x;
  float x = W[(size_t)k * 256 + n];
  u16 hi = f2bf(x);
  u16 lo = f2bf(x - bf2f(hi));
  size_t b = (size_t)n * 768 + k;
  dst[b] = hi;
  dst[b + 256] = hi;
  dst[b + 512] = lo;
}

// ---------- m97-style NT GEMM: C[M,N] f32 = A[M,K]bf16 * B[N,K]bf16^T ----------
// grid: (N/128, M/128, Z);  Z = split-K partitions, C has Z stacked outputs
__global__ __launch_bounds__(256) void gemm_nt(const u16* __restrict__ A,
                                               const u16* __restrict__ B,
                                               float* __restrict__ C,
                                               int M, int N, int K) {
  __shared__ __align__(16) u16 sA[128 * 32];
  __shared__ __align__(16) u16 sB[128 * 32];
  const int tid = threadIdx.x;
  const int wave = tid >> 6, lane = tid & 63;
  const int wr = wave >> 1, wc = wave & 1;
  const int rowBase = blockIdx.y * 128;
  const int colBase = blockIdx.x * 128;
  const int kchunk = K / gridDim.z;
  const int k0 = blockIdx.z * kchunk;
  float* Cp = C + (size_t)blockIdx.z * M * N;

  const int srow = lane >> 2;          // row within 16-row staging chunk
  const int skoff = (lane & 3) * 8;    // k element offset for this lane
  const int fr = lane & 15;
  const int fk = (lane >> 4) * 8;

  f32x4 acc[4][4] = {};

  for (int kt = k0; kt < k0 + kchunk; kt += 32) {
    for (int c = wave; c < 8; c += 4) {
      const u16* ga = A + (size_t)(rowBase + c * 16 + srow) * K + kt + skoff;
      gload_lds16(ga, &sA[c * 512]);
      const u16* gb = B + (size_t)(colBase + c * 16 + srow) * K + kt + skoff;
      gload_lds16(gb, &sB[c * 512]);
    }
    __syncthreads();
    bf16x8 af[4], bfr[4];
#pragma unroll
    for (int m = 0; m < 4; ++m)
      af[m] = *(const bf16x8*)&sA[(wr * 64 + m * 16 + fr) * 32 + fk];
#pragma unroll
    for (int n = 0; n < 4; ++n)
      bfr[n] = *(const bf16x8*)&sB[(wc * 64 + n * 16 + fr) * 32 + fk];
#pragma unroll
    for (int m = 0; m < 4; ++m)
#pragma unroll
      for (int n = 0; n < 4; ++n)
        acc[m][n] = __builtin_amdgcn_mfma_f32_16x16x32_bf16(af[m], bfr[n], acc[m][n], 0, 0, 0);
    __syncthreads();
  }
#pragma unroll
  for (int m = 0; m < 4; ++m)
#pragma unroll
    for (int n = 0; n < 4; ++n) {
      int r0 = rowBase + wr * 64 + m * 16 + (lane >> 4) * 4;
      int c0 = colBase + wc * 64 + n * 16 + fr;
#pragma unroll
      for (int r = 0; r < 4; ++r)
        Cp[(size_t)(r0 + r) * N + c0] = acc[m][n][r];
    }
}

// ---------- s_i, s_j ----------
__global__ __launch_bounds__(256) void k_sisj(const float* __restrict__ Wh,
                                              const float* __restrict__ r,
                                              float* __restrict__ s) {
  int wv = threadIdx.x >> 6, ln = threadIdx.x & 63;
  int row = blockIdx.x * 4 + wv;
  const float4 wh = *(const float4*)&Wh[(size_t)row * 256 + ln * 4];
  const float4 ri = *(const float4*)&r[ln * 4];
  const float4 rj = *(const float4*)&r[256 + ln * 4];
  float pi = wh.x * ri.x + wh.y * ri.y + wh.z * ri.z + wh.w * ri.w;
  float pj = wh.x * rj.x + wh.y * rj.y + wh.z * rj.z + wh.w * rj.w;
  for (int o = 32; o; o >>= 1) { pi += __shfl_xor(pi, o); pj += __shfl_xor(pj, o); }
  if (ln == 0) { s[row] = pi; s[NN + row] = pj; }
}

// ---------- phase-1 sparse GAT attention + gelu (wave per row) ----------
#define MAXD 128
__global__ __launch_bounds__(256) void k_attn1(const u64* __restrict__ B1,
                                               const float* __restrict__ s,
                                               const float* __restrict__ Wh,
                                               float* __restrict__ h) {
  __shared__ int idxs[4][MAXD];
  __shared__ float ww[4][MAXD];
  __shared__ int cnts[4];
  int wv = threadIdx.x >> 6, ln = threadIdx.x & 63;
  int row = blockIdx.x * 4 + wv;
  if (ln == 0) cnts[wv] = 0;
  __syncthreads();
  u64 w = B1[(size_t)row * 64 + ln];
  while (w) {
    int b = __builtin_ctzll(w);
    w &= w - 1;
    int p = atomicAdd(&cnts[wv], 1);
    if (p < MAXD) idxs[wv][p] = ln * 64 + b;
  }
  __syncthreads();
  int cnt = cnts[wv] < MAXD ? cnts[wv] : MAXD;
  float si = s[row];
  for (int i = ln; i < cnt; i += 64) {
    float v = si + s[NN + idxs[wv][i]];
    ww[wv][i] = v > 0.f ? v : 0.2f * v;     // leaky_relu
  }
  __syncthreads();
  float mx = -1e30f;
  for (int i = ln; i < cnt; i += 64) mx = fmaxf(mx, ww[wv][i]);
  for (int o = 32; o; o >>= 1) mx = fmaxf(mx, __shfl_xor(mx, o));
  float sm = 0.f;
  for (int i = ln; i < cnt; i += 64) sm += __expf(ww[wv][i] - mx);
  for (int o = 32; o; o >>= 1) sm += __shfl_xor(sm, o);
  float inv = 1.0f / sm;
  for (int i = ln; i < cnt; i += 64) ww[wv][i] = __expf(ww[wv][i] - mx) * inv;
  __syncthreads();
  float a0 = 0, a1 = 0, a2 = 0, a3 = 0;
  for (int t = 0; t < cnt; ++t) {
    float wgt = ww[wv][t];
    const float4 v = *(const float4*)&Wh[(size_t)idxs[wv][t] * 256 + ln * 4];
    a0 = fmaf(wgt, v.x, a0); a1 = fmaf(wgt, v.y, a1);
    a2 = fmaf(wgt, v.z, a2); a3 = fmaf(wgt, v.w, a3);
  }
  float4 o4;
  o4.x = gelu_f(a0); o4.y = gelu_f(a1); o4.z = gelu_f(a2); o4.w = gelu_f(a3);
  *(float4*)&h[(size_t)row * 256 + ln * 4] = o4;
}

// ---------- h [4096,256] f32 -> hT [256,4096] bf16 ----------
__global__ __launch_bounds__(256) void k_transpose(const float* __restrict__ h,
                                                   u16* __restrict__ hT) {
  __shared__ u16 tile[64][65];
  int t = threadIdx.x;
  int bx = blockIdx.x & 3;        // col block of h (256/64)
  int by = blockIdx.x >> 2;       // row block of h (4096/64)
  for (int rr = (t >> 6); rr < 64; rr += 4)
    tile[rr][t & 63] = f2bf(h[(size_t)(by * 64 + rr) * 256 + bx * 64 + (t & 63)]);
  __syncthreads();
  for (int jj = (t >> 6); jj < 64; jj += 4)
    hT[(size_t)(bx * 64 + jj) * NN + by * 64 + (t & 63)] = tile[t & 63][jj];
}

// ---------- combined 3-hop softmax weights: Wc = w1+w2+w3 (block per row) ----------
__global__ __launch_bounds__(256) void k_wc(const float* __restrict__ scores,
                                            const u64* __restrict__ B1,
                                            const u64* __restrict__ B2,
                                            const u64* __restrict__ B3,
                                            u16* __restrict__ Wc) {
  __shared__ float srow[NN];
  __shared__ u64 m1[64], m2[64], m3[64];
  __shared__ float red[3][4];
  __shared__ float red2[3][4];
  const int t = threadIdx.x;
  const int row = blockIdx.x;
  const size_t rbase = (size_t)row * NN;
  if (t < 64) m1[t] = B1[(size_t)row * 64 + t];
  else if (t < 128) m2[t - 64] = B2[(size_t)row * 64 + (t - 64)];
  else if (t < 192) m3[t - 128] = B3[(size_t)row * 64 + (t - 128)];
  for (int c = t; c < NN; c += 256) srow[c] = scores[rbase + c];
  __syncthreads();
  float mx1 = -1e30f, mx2 = -1e30f, mx3 = -1e30f;
  for (int c = t; c < NN; c += 256) {
    int w = c >> 6; u64 bit = 1ull << (c & 63);
    if (m3[w] & bit) {
      float v = srow[c];
      mx3 = fmaxf(mx3, v);
      if (m2[w] & bit) mx2 = fmaxf(mx2, v);
      if (m1[w] & bit) mx1 = fmaxf(mx1, v);
    }
  }
  for (int o = 32; o; o >>= 1) {
    mx1 = fmaxf(mx1, __shfl_xor(mx1, o));
    mx2 = fmaxf(mx2, __shfl_xor(mx2, o));
    mx3 = fmaxf(mx3, __shfl_xor(mx3, o));
  }
  if ((t & 63) == 0) { int wv = t >> 6; red[0][wv] = mx1; red[1][wv] = mx2; red[2][wv] = mx3; }
  __syncthreads();
  mx1 = fmaxf(fmaxf(red[0][0], red[0][1]), fmaxf(red[0][2], red[0][3]));
  mx2 = fmaxf(fmaxf(red[1][0], red[1][1]), fmaxf(red[1][2], red[1][3]));
  mx3 = fmaxf(fmaxf(red[2][0], red[2][1]), fmaxf(red[2][2], red[2][3]));
  float s1 = 0.f, s2 = 0.f, s3 = 0.f;
  for (int c = t; c < NN; c += 256) {
    int w = c >> 6; u64 bit = 1ull << (c & 63);
    if (m3[w] & bit) {
      float v = srow[c];
      s3 += __expf(v - mx3);
      if (m2[w] & bit) s2 += __expf(v - mx2);
      if (m1[w] & bit) s1 += __expf(v - mx1);
    }
  }
  for (int o = 32; o; o >>= 1) {
    s1 += __shfl_xor(s1, o); s2 += __shfl_xor(s2, o); s3 += __shfl_xor(s3, o);
  }
  if ((t & 63) == 0) { int wv = t >> 6; red2[0][wv] = s1; red2[1][wv] = s2; red2[2][wv] = s3; }
  __syncthreads();
  s1 = red2[0][0] + red2[0][1] + red2[0][2] + red2[0][3];
  s2 = red2[1][0] + red2[1][1] + red2[1][2] + red2[1][3];
  s3 = red2[2][0] + red2[2][1] + red2[2][2] + red2[2][3];
  float inv1 = 1.0f / s1, inv2 = 1.0f / s2, inv3 = 1.0f / s3;
  for (int c = t; c < NN; c += 256) {
    int w = c >> 6; u64 bit = 1ull << (c & 63);
    float wgt = 0.f;
    if (m3[w] & bit) {
      float v = srow[c];
      wgt = __expf(v - mx3) * inv3;
      if (m2[w] & bit) wgt += __expf(v - mx2) * inv2;
      if (m1[w] & bit) wgt += __expf(v - mx1) * inv1;
    }
    Wc[rbase + c] = f2bf(wgt);
  }
}

// ---------- final: out = (h + sum tmp_z) @ W_out + b_out ----------
__global__ __launch_bounds__(128) void k_final(const float* __restrict__ h,
                                               const float* __restrict__ tmp,
                                               const float* __restrict__ Wout,
                                               const float* __restrict__ bout,
                                               float* __restrict__ out) {
  __shared__ float rrow[8][256];
  int t = threadIdx.x;
  int row0 = blockIdx.x * 8;
  const size_t P = (size_t)NN * 256;
  for (int i = t; i < 8 * 256; i += 128) {
    int rr = i >> 8, k = i & 255;
    size_t idx = (size_t)(row0 + rr) * 256 + k;
    rrow[rr][k] = h[idx] + tmp[idx] + tmp[idx + P] + tmp[idx + 2 * P] + tmp[idx + 3 * P];
  }
  __syncthreads();
  float b = bout[t];
  float acc[8];
#pragma unroll
  for (int i = 0; i < 8; ++i) acc[i] = b;
  for (int k = 0; k < 256; ++k) {
    float w = Wout[k * 128 + t];
#pragma unroll
    for (int i = 0; i < 8; ++i) acc[i] = fmaf(rrow[i][k], w, acc[i]);
  }
#pragma unroll
  for (int i = 0; i < 8; ++i) out[(size_t)(row0 + i) * 128 + t] = acc[i];
}

// ---------- host ----------
extern "C" void kernel_launch(void* const* d_in, const int* in_sizes, int n_in,
                              void* d_out, int out_size, void* d_ws, size_t ws_size,
                              hipStream_t stream) {
  const float* X    = (const float*)d_in[0];
  const float* A    = (const float*)d_in[1];
  const float* W_s  = (const float*)d_in[2];
  const float* r    = (const float*)d_in[3];
  const float* W_l  = (const float*)d_in[4];
  const float* Wout = (const float*)d_in[5];
  const float* bout = (const float*)d_in[6];
  float* out = (float*)d_out;

  char* wp = (char*)d_ws;
  auto take = [&](size_t n) { char* p = wp; wp += (n + 255) & ~(size_t)255; return p; };
  u64* B1     = (u64*)take((size_t)NN * 64 * 8);      // 2 MB
  u64* B2     = (u64*)take((size_t)NN * 64 * 8);      // 2 MB
  u64* B3     = (u64*)take((size_t)NN * 64 * 8);      // 2 MB
  float* Wh   = (float*)take((size_t)NN * 256 * 4);   // 4 MB
  float* sv   = (float*)take((size_t)2 * NN * 4);     // 32 KB
  float* h    = (float*)take((size_t)NN * 256 * 4);   // 4 MB
  u16* hT     = (u16*)take((size_t)256 * NN * 2);     // 2 MB
  u16* hsp    = (u16*)take((size_t)NN * 768 * 2);     // 6 MB
  u16* Wasp   = (u16*)take((size_t)NN * 768 * 2);     // 6 MB
  u16* Xsp    = (u16*)take((size_t)NN * 768 * 2);     // 6 MB (reused as Wa f32)
  float* Wa   = (float*)Xsp;                          // alias: Xsp dead after Wh GEMM
  u16* WsT    = (u16*)take((size_t)256 * 768 * 2);
  u16* WlT    = (u16*)take((size_t)256 * 768 * 2);
  float* scores = (float*)take((size_t)NN * NN * 4);  // 64 MB (reused as tmp 16 MB)
  float* tmp  = scores;                               // alias: scores dead after k_wc
  u16* Wc     = (u16*)take((size_t)NN * NN * 2);      // 32 MB
  (void)n_in; (void)in_sizes; (void)out_size; (void)ws_size;

  // masks
  k_bitset<<<NN / 4, 256, 0, stream>>>(A, B1);
  k_expand<<<NN / 4, 256, 0, stream>>>(B1, B1, B2);
  k_expand<<<NN / 4, 256, 0, stream>>>(B2, B1, B3);
  // weight prep
  k_splitT<<<256, 256, 0, stream>>>(W_s, WsT);
  k_splitT<<<256, 256, 0, stream>>>(W_l, WlT);
  k_split<<<NN, 256, 0, stream>>>(X, Xsp, 1);
  // Wh = X @ W_s   (split-bf16, K=768)
  gemm_nt<<<dim3(2, 32, 1), 256, 0, stream>>>(Xsp, WsT, Wh, NN, 256, 768);
  k_sisj<<<NN / 4, 256, 0, stream>>>(Wh, r, sv);
  k_attn1<<<NN / 4, 256, 0, stream>>>(B1, sv, Wh, h);
  k_split<<<NN, 256, 0, stream>>>(h, hsp, 1);
  k_transpose<<<256, 256, 0, stream>>>(h, hT);
  // Wa = h @ W_l
  gemm_nt<<<dim3(2, 32, 1), 256, 0, stream>>>(hsp, WlT, Wa, NN, 256, 768);
  k_split<<<NN, 256, 0, stream>>>(Wa, Wasp, 0);
  // scores = h @ Wa^T  (split-bf16, near-f32)
  gemm_nt<<<dim3(32, 32, 1), 256, 0, stream>>>(hsp, Wasp, scores, NN, NN, 768);
  // combined 3-hop softmax weights
  k_wc<<<NN, 256, 0, stream>>>(scores, B1, B2, B3, Wc);
  // tmp = Wc @ h   (split-K=4 over K=4096)
  gemm_nt<<<dim3(2, 32, 4), 256, 0, stream>>>(Wc, hT, tmp, NN, 256, NN);
  // out = (h + tmp) @ W_out + b_out
  k_final<<<NN / 8, 128, 0, stream>>>(h, tmp, Wout, bout, out);
}

// Round 4
// 378.681 us; speedup vs baseline: 1.0604x; 1.0604x over previous
//
#include <hip/hip_runtime.h>
#include <cstdint>
#include <cstddef>

typedef unsigned long long u64;
typedef unsigned short u16;
typedef unsigned int u32;
typedef __bf16 bf16x8 __attribute__((ext_vector_type(8)));
typedef float f32x4 __attribute__((ext_vector_type(4)));

#define NN 4096
#define HIDD 256

// ---------- helpers ----------
__device__ __forceinline__ u16 f2bf(float f) {
  unsigned int u = __float_as_uint(f);
  u = u + 0x7FFFu + ((u >> 16) & 1u);   // RNE
  return (u16)(u >> 16);
}
__device__ __forceinline__ float bf2f(u16 h) {
  return __uint_as_float(((unsigned int)h) << 16);
}
__device__ __forceinline__ float gelu_f(float x) {
  return 0.5f * x * (1.0f + erff(x * 0.70710678118654752f));
}
__device__ __forceinline__ void gload_lds16(const u16* g, u16* l) {
  __builtin_amdgcn_global_load_lds((const __attribute__((address_space(1))) void*)g,
                                   (__attribute__((address_space(3))) void*)l, 16, 0, 0);
}

// ---------- K0: adjacency -> bitset rows (wave per row, ballot) ----------
__global__ __launch_bounds__(256) void k_bitset(const float* __restrict__ A, u64* __restrict__ B1) {
  int wv = threadIdx.x >> 6, ln = threadIdx.x & 63;
  int row = blockIdx.x * 4 + wv;
  const float* ar = A + (size_t)row * NN;
#pragma unroll 4
  for (int w = 0; w < 64; ++w) {
    float v = ar[w * 64 + ln];
    u64 m = __ballot(v != 0.0f);
    if (ln == 0) B1[(size_t)row * 64 + w] = m;
  }
}

// ---------- boolean mat-power expansion (wave per row) ----------
__global__ __launch_bounds__(256) void k_expand(const u64* __restrict__ src,
                                                const u64* __restrict__ base,
                                                u64* __restrict__ dst) {
  int wv = threadIdx.x >> 6, ln = threadIdx.x & 63;
  int row = blockIdx.x * 4 + wv;
  u64 acc = 0;
  for (int w = 0; w < 64; ++w) {
    u64 word = src[(size_t)row * 64 + w];   // uniform across lanes
    while (word) {
      int b = __builtin_ctzll(word);
      word &= word - 1;
      int m = w * 64 + b;
      acc |= base[(size_t)m * 64 + ln];     // coalesced 512B
    }
  }
  dst[(size_t)row * 64 + ln] = acc;
}

// ---------- split f32 [R,256] -> bf16 [R,768] hi/lo concat ----------
// pat=1 (A-operand): (hi, lo, hi);  pat=0 (B-operand): (hi, hi, lo)
__global__ __launch_bounds__(256) void k_split(const float* __restrict__ src,
                                               u16* __restrict__ dst, int pat) {
  int rrow = blockIdx.x, c = threadIdx.x;
  float x = src[(size_t)rrow * 256 + c];
  u16 hi = f2bf(x);
  u16 lo = f2bf(x - bf2f(hi));
  size_t b = (size_t)rrow * 768 + c;
  dst[b] = hi;
  dst[b + 256] = pat ? lo : hi;
  dst[b + 512] = pat ? hi : lo;
}

// ---------- transpose+split both weights [256,256] -> [256,768] (B-pattern) ----------
__global__ __launch_bounds__(256) void k_splitT2(const float* __restrict__ W0,
                                                 const float* __restrict__ W1,
                                                 u16* __restrict__ d0,
                                                 u16* __restrict__ d1) {
  int blk = blockIdx.x;
  const float* W = blk < 256 ? W0 : W1;
  u16* dst = blk < 256 ? d0 : d1;
  int n = blk & 255, k = threadIdx.x;
  float x = W[(size_t)k * 256 + n];
  u16 hi = f2bf(x);
  u16 lo = f2bf(x - bf2f(hi));
  size_t b = (size_t)n * 768 + k;
  dst[b] = hi;
  dst[b + 256] = hi;
  dst[b + 512] = lo;
}

// ---------- m97-style NT GEMM: C[M,N] f32 = A[M,K]bf16 * B[N,K]bf16^T ----------
// grid: (N/128, M/128, Z);  Z = split-K partitions, C has Z stacked outputs
__global__ __launch_bounds__(256) void gemm_nt(const u16* __restrict__ A,
                                               const u16* __restrict__ B,
                                               float* __restrict__ C,
                                               int M, int N, int K) {
  __shared__ __align__(16) u16 sA[128 * 32];
  __shared__ __align__(16) u16 sB[128 * 32];
  const int tid = threadIdx.x;
  const int wave = tid >> 6, lane = tid & 63;
  const int wr = wave >> 1, wc = wave & 1;

  // T1: bijective XCD-chunked swizzle (z==1 grids only; nwg%8==0 for all our z==1 grids)
  int bx = blockIdx.x, by = blockIdx.y;
  {
    int nwg = gridDim.x * gridDim.y;
    if (gridDim.z == 1 && (nwg & 7) == 0) {
      int bid = by * gridDim.x + bx;
      int cpx = nwg >> 3;
      bid = (bid & 7) * cpx + (bid >> 3);
      bx = bid % gridDim.x;
      by = bid / gridDim.x;
    }
  }

  const int rowBase = by * 128;
  const int colBase = bx * 128;
  const int kchunk = K / gridDim.z;
  const int k0 = blockIdx.z * kchunk;
  float* Cp = C + (size_t)blockIdx.z * M * N;

  const int srow = lane >> 2;          // row within 16-row staging chunk
  const int skoff = (lane & 3) * 8;    // k element offset for this lane
  const int fr = lane & 15;
  const int fk = (lane >> 4) * 8;

  f32x4 acc[4][4] = {};

  for (int kt = k0; kt < k0 + kchunk; kt += 32) {
    for (int c = wave; c < 8; c += 4) {
      const u16* ga = A + (size_t)(rowBase + c * 16 + srow) * K + kt + skoff;
      gload_lds16(ga, &sA[c * 512]);
      const u16* gb = B + (size_t)(colBase + c * 16 + srow) * K + kt + skoff;
      gload_lds16(gb, &sB[c * 512]);
    }
    __syncthreads();
    bf16x8 af[4], bfr[4];
#pragma unroll
    for (int m = 0; m < 4; ++m)
      af[m] = *(const bf16x8*)&sA[(wr * 64 + m * 16 + fr) * 32 + fk];
#pragma unroll
    for (int n = 0; n < 4; ++n)
      bfr[n] = *(const bf16x8*)&sB[(wc * 64 + n * 16 + fr) * 32 + fk];
#pragma unroll
    for (int m = 0; m < 4; ++m)
#pragma unroll
      for (int n = 0; n < 4; ++n)
        acc[m][n] = __builtin_amdgcn_mfma_f32_16x16x32_bf16(af[m], bfr[n], acc[m][n], 0, 0, 0);
    __syncthreads();
  }
#pragma unroll
  for (int m = 0; m < 4; ++m)
#pragma unroll
    for (int n = 0; n < 4; ++n) {
      int r0 = rowBase + wr * 64 + m * 16 + (lane >> 4) * 4;
      int c0 = colBase + wc * 64 + n * 16 + fr;
#pragma unroll
      for (int r = 0; r < 4; ++r)
        Cp[(size_t)(r0 + r) * N + c0] = acc[m][n][r];
    }
}

// ---------- s_i, s_j ----------
__global__ __launch_bounds__(256) void k_sisj(const float* __restrict__ Wh,
                                              const float* __restrict__ r,
                                              float* __restrict__ s) {
  int wv = threadIdx.x >> 6, ln = threadIdx.x & 63;
  int row = blockIdx.x * 4 + wv;
  const float4 wh = *(const float4*)&Wh[(size_t)row * 256 + ln * 4];
  const float4 ri = *(const float4*)&r[ln * 4];
  const float4 rj = *(const float4*)&r[256 + ln * 4];
  float pi = wh.x * ri.x + wh.y * ri.y + wh.z * ri.z + wh.w * ri.w;
  float pj = wh.x * rj.x + wh.y * rj.y + wh.z * rj.z + wh.w * rj.w;
  for (int o = 32; o; o >>= 1) { pi += __shfl_xor(pi, o); pj += __shfl_xor(pj, o); }
  if (ln == 0) { s[row] = pi; s[NN + row] = pj; }
}

// ---------- phase-1 sparse GAT attention + gelu (wave per row) ----------
#define MAXD 128
__global__ __launch_bounds__(256) void k_attn1(const u64* __restrict__ B1,
                                               const float* __restrict__ s,
                                               const float* __restrict__ Wh,
                                               float* __restrict__ h) {
  __shared__ int idxs[4][MAXD];
  __shared__ float ww[4][MAXD];
  __shared__ int cnts[4];
  int wv = threadIdx.x >> 6, ln = threadIdx.x & 63;
  int row = blockIdx.x * 4 + wv;
  if (ln == 0) cnts[wv] = 0;
  __syncthreads();
  u64 w = B1[(size_t)row * 64 + ln];
  while (w) {
    int b = __builtin_ctzll(w);
    w &= w - 1;
    int p = atomicAdd(&cnts[wv], 1);
    if (p < MAXD) idxs[wv][p] = ln * 64 + b;
  }
  __syncthreads();
  int cnt = cnts[wv] < MAXD ? cnts[wv] : MAXD;
  float si = s[row];
  for (int i = ln; i < cnt; i += 64) {
    float v = si + s[NN + idxs[wv][i]];
    ww[wv][i] = v > 0.f ? v : 0.2f * v;     // leaky_relu
  }
  __syncthreads();
  float mx = -1e30f;
  for (int i = ln; i < cnt; i += 64) mx = fmaxf(mx, ww[wv][i]);
  for (int o = 32; o; o >>= 1) mx = fmaxf(mx, __shfl_xor(mx, o));
  float sm = 0.f;
  for (int i = ln; i < cnt; i += 64) sm += __expf(ww[wv][i] - mx);
  for (int o = 32; o; o >>= 1) sm += __shfl_xor(sm, o);
  float inv = 1.0f / sm;
  for (int i = ln; i < cnt; i += 64) ww[wv][i] = __expf(ww[wv][i] - mx) * inv;
  __syncthreads();
  float a0 = 0, a1 = 0, a2 = 0, a3 = 0;
  for (int t = 0; t < cnt; ++t) {
    float wgt = ww[wv][t];
    const float4 v = *(const float4*)&Wh[(size_t)idxs[wv][t] * 256 + ln * 4];
    a0 = fmaf(wgt, v.x, a0); a1 = fmaf(wgt, v.y, a1);
    a2 = fmaf(wgt, v.z, a2); a3 = fmaf(wgt, v.w, a3);
  }
  float4 o4;
  o4.x = gelu_f(a0); o4.y = gelu_f(a1); o4.z = gelu_f(a2); o4.w = gelu_f(a3);
  *(float4*)&h[(size_t)row * 256 + ln * 4] = o4;
}

// ---------- h [4096,256] f32 -> hT [256,4096] bf16 ----------
__global__ __launch_bounds__(256) void k_transpose(const float* __restrict__ h,
                                                   u16* __restrict__ hT) {
  __shared__ u16 tile[64][65];
  int t = threadIdx.x;
  int bx = blockIdx.x & 3;        // col block of h (256/64)
  int by = blockIdx.x >> 2;       // row block of h (4096/64)
  for (int rr = (t >> 6); rr < 64; rr += 4)
    tile[rr][t & 63] = f2bf(h[(size_t)(by * 64 + rr) * 256 + bx * 64 + (t & 63)]);
  __syncthreads();
  for (int jj = (t >> 6); jj < 64; jj += 4)
    hT[(size_t)(bx * 64 + jj) * NN + by * 64 + (t & 63)] = tile[t & 63][jj];
}

// ---------- combined 3-hop softmax weights: Wc = w1+w2+w3 ----------
// Register-resident: thread t owns columns c(g,j) = g*1024 + 4t + j.
// Tier-3 dense via per-lane nibble mask tests; tier-1/2 (avg ~93 cols/row)
// sparse on wave 0 with their own maxes (numerically identical to nested-tier
// version). Pass C writes ALL columns (0 where not in mask3); sparse pass
// overwrites tier-1/2 columns after a barrier (syncthreads drains vmcnt).
__global__ __launch_bounds__(256) void k_wc(const float* __restrict__ scores,
                                            const u64* __restrict__ B1,
                                            const u64* __restrict__ B2,
                                            const u64* __restrict__ B3,
                                            u16* __restrict__ Wc) {
  __shared__ u64 sm3[64];
  __shared__ float rmax[4], rsum[4];
  const int t = threadIdx.x;
  const int wv = t >> 6, ln = t & 63;
  const int row = blockIdx.x;
  const size_t rbase = (size_t)row * NN;

  if (t < 64) sm3[t] = B3[(size_t)row * 64 + t];
  // dense register load: 4x dwordx4, 1KB per wave per load
  f32x4 v[4];
  const f32x4* sp = (const f32x4*)(scores + rbase);
#pragma unroll
  for (int g = 0; g < 4; ++g) v[g] = sp[g * 256 + t];
  // wave0 sparse tier masks (per-lane word)
  u64 w2 = 0, w1 = 0;
  if (wv == 0) {
    w2 = B2[(size_t)row * 64 + ln];
    w1 = B1[(size_t)row * 64 + ln];
  }
  __syncthreads();

  const int wi = t >> 4;            // mask word sub-index (per 1024-col group)
  const int sb = (t & 15) * 4;      // bit base within word (j-invariant)
  u32 nib[4];
  float mx3 = -3e38f;
#pragma unroll
  for (int g = 0; g < 4; ++g) {
    u64 wrd = sm3[g * 16 + wi];
    u32 half = (sb < 32) ? (u32)wrd : (u32)(wrd >> 32);
    nib[g] = (half >> (sb & 31)) & 0xFu;
#pragma unroll
    for (int j = 0; j < 4; ++j)
      if (nib[g] & (1u << j)) mx3 = fmaxf(mx3, v[g][j]);
  }
  for (int o = 32; o; o >>= 1) mx3 = fmaxf(mx3, __shfl_xor(mx3, o));
  if (ln == 0) rmax[wv] = mx3;

  // wave0: sparse tier-2/1 maxes (scores row is L1/L2-hot)
  float mx2 = -3e38f, mx1 = -3e38f;
  if (wv == 0) {
    u64 w = w2;
    while (w) {
      int b = __builtin_ctzll(w); w &= w - 1;
      float sc = scores[rbase + ln * 64 + b];
      mx2 = fmaxf(mx2, sc);
      if (w1 & (1ull << b)) mx1 = fmaxf(mx1, sc);
    }
    for (int o = 32; o; o >>= 1) {
      mx2 = fmaxf(mx2, __shfl_xor(mx2, o));
      mx1 = fmaxf(mx1, __shfl_xor(mx1, o));
    }
  }
  __syncthreads();
  mx3 = fmaxf(fmaxf(rmax[0], rmax[1]), fmaxf(rmax[2], rmax[3]));

  // pass B: e = exp(v - mx3) masked; overwrite regs; accumulate s3
  float s3 = 0.f;
#pragma unroll
  for (int g = 0; g < 4; ++g)
#pragma unroll
    for (int j = 0; j < 4; ++j) {
      float e = __expf(v[g][j] - mx3);
      e = (nib[g] & (1u << j)) ? e : 0.f;
      v[g][j] = e;
      s3 += e;
    }
  for (int o = 32; o; o >>= 1) s3 += __shfl_xor(s3, o);
  if (ln == 0) rsum[wv] = s3;

  // wave0: sparse tier-2/1 sums
  float s2 = 1.f, s1 = 1.f;
  if (wv == 0) {
    float s2p = 0.f, s1p = 0.f;
    u64 w = w2;
    while (w) {
      int b = __builtin_ctzll(w); w &= w - 1;
      float sc = scores[rbase + ln * 64 + b];
      s2p += __expf(sc - mx2);
      if (w1 & (1ull << b)) s1p += __expf(sc - mx1);
    }
    for (int o = 32; o; o >>= 1) {
      s2p += __shfl_xor(s2p, o);
      s1p += __shfl_xor(s1p, o);
    }
    s2 = s2p; s1 = s1p;
  }
  __syncthreads();
  s3 = rsum[0] + rsum[1] + rsum[2] + rsum[3];
  float inv3 = 1.0f / s3;

  // pass C: write all columns (tier-3 weight; 0 outside mask3)
#pragma unroll
  for (int g = 0; g < 4; ++g) {
    u16 o0 = f2bf(v[g][0] * inv3), o1 = f2bf(v[g][1] * inv3);
    u16 o2 = f2bf(v[g][2] * inv3), o3 = f2bf(v[g][3] * inv3);
    uint2 pk;
    pk.x = (u32)o0 | ((u32)o1 << 16);
    pk.y = (u32)o2 | ((u32)o3 << 16);
    *(uint2*)&Wc[rbase + (size_t)g * 1024 + t * 4] = pk;
  }
  __syncthreads();   // pass-C stores drained before sparse overwrite

  // wave0: overwrite tier-2/1 columns with full combined weight
  if (wv == 0) {
    float inv2 = 1.0f / s2, inv1 = 1.0f / s1;
    u64 w = w2;
    while (w) {
      int b = __builtin_ctzll(w); w &= w - 1;
      int c = ln * 64 + b;
      float sc = scores[rbase + c];
      float wgt = __expf(sc - mx3) * inv3 + __expf(sc - mx2) * inv2;
      if (w1 & (1ull << b)) wgt += __expf(sc - mx1) * inv1;
      Wc[rbase + c] = f2bf(wgt);
    }
  }
}

// ---------- final: out = (h + sum tmp_z) @ W_out + b_out ----------
__global__ __launch_bounds__(128) void k_final(const float* __restrict__ h,
                                               const float* __restrict__ tmp,
                                               const float* __restrict__ Wout,
                                               const float* __restrict__ bout,
                                               float* __restrict__ out) {
  __shared__ float rrow[8][256];
  int t = threadIdx.x;
  int row0 = blockIdx.x * 8;
  const size_t P = (size_t)NN * 256;
  for (int i = t; i < 8 * 256; i += 128) {
    int rr = i >> 8, k = i & 255;
    size_t idx = (size_t)(row0 + rr) * 256 + k;
    rrow[rr][k] = h[idx] + tmp[idx] + tmp[idx + P] + tmp[idx + 2 * P] + tmp[idx + 3 * P];
  }
  __syncthreads();
  float b = bout[t];
  float acc[8];
#pragma unroll
  for (int i = 0; i < 8; ++i) acc[i] = b;
  for (int k = 0; k < 256; ++k) {
    float w = Wout[k * 128 + t];
#pragma unroll
    for (int i = 0; i < 8; ++i) acc[i] = fmaf(rrow[i][k], w, acc[i]);
  }
#pragma unroll
  for (int i = 0; i < 8; ++i) out[(size_t)(row0 + i) * 128 + t] = acc[i];
}

// ---------- host ----------
extern "C" void kernel_launch(void* const* d_in, const int* in_sizes, int n_in,
                              void* d_out, int out_size, void* d_ws, size_t ws_size,
                              hipStream_t stream) {
  const float* X    = (const float*)d_in[0];
  const float* A    = (const float*)d_in[1];
  const float* W_s  = (const float*)d_in[2];
  const float* r    = (const float*)d_in[3];
  const float* W_l  = (const float*)d_in[4];
  const float* Wout = (const float*)d_in[5];
  const float* bout = (const float*)d_in[6];
  float* out = (float*)d_out;

  char* wp = (char*)d_ws;
  auto take = [&](size_t n) { char* p = wp; wp += (n + 255) & ~(size_t)255; return p; };
  u64* B1     = (u64*)take((size_t)NN * 64 * 8);      // 2 MB
  u64* B2     = (u64*)take((size_t)NN * 64 * 8);      // 2 MB
  u64* B3     = (u64*)take((size_t)NN * 64 * 8);      // 2 MB
  float* Wh   = (float*)take((size_t)NN * 256 * 4);   // 4 MB
  float* sv   = (float*)take((size_t)2 * NN * 4);     // 32 KB
  float* h    = (float*)take((size_t)NN * 256 * 4);   // 4 MB
  u16* hT     = (u16*)take((size_t)256 * NN * 2);     // 2 MB
  u16* hsp    = (u16*)take((size_t)NN * 768 * 2);     // 6 MB
  u16* Wasp   = (u16*)take((size_t)NN * 768 * 2);     // 6 MB
  u16* Xsp    = (u16*)take((size_t)NN * 768 * 2);     // 6 MB (reused as Wa f32)
  float* Wa   = (float*)Xsp;                          // alias: Xsp dead after Wh GEMM
  u16* WsT    = (u16*)take((size_t)256 * 768 * 2);
  u16* WlT    = (u16*)take((size_t)256 * 768 * 2);
  float* scores = (float*)take((size_t)NN * NN * 4);  // 64 MB (reused as tmp 16 MB)
  float* tmp  = scores;                               // alias: scores dead after k_wc
  u16* Wc     = (u16*)take((size_t)NN * NN * 2);      // 32 MB
  (void)n_in; (void)in_sizes; (void)out_size; (void)ws_size;

  // masks
  k_bitset<<<NN / 4, 256, 0, stream>>>(A, B1);
  k_expand<<<NN / 4, 256, 0, stream>>>(B1, B1, B2);
  k_expand<<<NN / 4, 256, 0, stream>>>(B2, B1, B3);
  // weight prep (both transposed splits in one launch)
  k_splitT2<<<512, 256, 0, stream>>>(W_s, W_l, WsT, WlT);
  k_split<<<NN, 256, 0, stream>>>(X, Xsp, 1);
  // Wh = X @ W_s   (split-bf16, K=768)
  gemm_nt<<<dim3(2, 32, 1), 256, 0, stream>>>(Xsp, WsT, Wh, NN, 256, 768);
  k_sisj<<<NN / 4, 256, 0, stream>>>(Wh, r, sv);
  k_attn1<<<NN / 4, 256, 0, stream>>>(B1, sv, Wh, h);
  k_split<<<NN, 256, 0, stream>>>(h, hsp, 1);
  k_transpose<<<256, 256, 0, stream>>>(h, hT);
  // Wa = h @ W_l
  gemm_nt<<<dim3(2, 32, 1), 256, 0, stream>>>(hsp, WlT, Wa, NN, 256, 768);
  k_split<<<NN, 256, 0, stream>>>(Wa, Wasp, 0);
  // scores = h @ Wa^T  (split-bf16, near-f32)
  gemm_nt<<<dim3(32, 32, 1), 256, 0, stream>>>(hsp, Wasp, scores, NN, NN, 768);
  // combined 3-hop softmax weights
  k_wc<<<NN, 256, 0, stream>>>(scores, B1, B2, B3, Wc);
  // tmp = Wc @ h   (split-K=4 over K=4096)
  gemm_nt<<<dim3(2, 32, 4), 256, 0, stream>>>(Wc, hT, tmp, NN, 256, NN);
  // out = (h + tmp) @ W_out + b_out
  k_final<<<NN / 8, 128, 0, stream>>>(h, tmp, Wout, bout, out);
}

// Round 7
// 300.643 us; speedup vs baseline: 1.3356x; 1.2596x over previous
//
#include <hip/hip_runtime.h>
#include <cstdint>
#include <cstddef>

typedef unsigned long long u64;
typedef unsigned short u16;
typedef unsigned int u32;
typedef __bf16 bf16x8 __attribute__((ext_vector_type(8)));
typedef float f32x4 __attribute__((ext_vector_type(4)));

#define NN 4096
#define HIDD 256

// ---------- helpers ----------
__device__ __forceinline__ u16 f2bf(float f) {
  unsigned int u = __float_as_uint(f);
  u = u + 0x7FFFu + ((u >> 16) & 1u);   // RNE
  return (u16)(u >> 16);
}
__device__ __forceinline__ float bf2f(u16 h) {
  return __uint_as_float(((unsigned int)h) << 16);
}
__device__ __forceinline__ float gelu_f(float x) {
  return 0.5f * x * (1.0f + erff(x * 0.70710678118654752f));
}
__device__ __forceinline__ void gload_lds16(const u16* g, u16* l) {
  __builtin_amdgcn_global_load_lds((const __attribute__((address_space(1))) void*)g,
                                   (__attribute__((address_space(3))) void*)l, 16, 0, 0);
}

// ---------- K0: adjacency -> bitset rows (float4 loads + nibble LDS assembly) ----------
// Row has 4096 cols = 1024 nibbles (nibble p covers cols 4p..4p+3).
__global__ __launch_bounds__(256) void k_bitset(const float* __restrict__ A, u64* __restrict__ B1) {
  __shared__ unsigned char nib[4][1024];   // R5 bug: was [4][256] -> LDS overflow
  int wv = threadIdx.x >> 6, ln = threadIdx.x & 63;
  int row = blockIdx.x * 4 + wv;
  const float4* ar = (const float4*)(A + (size_t)row * NN);
#pragma unroll
  for (int it = 0; it < 16; ++it) {
    float4 v = ar[it * 64 + ln];
    unsigned n = (v.x != 0.f ? 1u : 0u) | (v.y != 0.f ? 2u : 0u) |
                 (v.z != 0.f ? 4u : 0u) | (v.w != 0.f ? 8u : 0u);
    nib[wv][it * 64 + ln] = (unsigned char)n;
  }
  __syncthreads();
  // lane ln assembles word ln from nibble positions 16*ln .. 16*ln+15
  const u32* np4 = (const u32*)&nib[wv][ln * 16];
  u64 word = 0;
#pragma unroll
  for (int q = 0; q < 4; ++q) {
    u32 four = np4[q];
    u64 part = (u64)(four & 0xFu) | ((u64)((four >> 8) & 0xFu) << 4) |
               ((u64)((four >> 16) & 0xFu) << 8) | ((u64)((four >> 24) & 0xFu) << 12);
    word |= part << (16 * q);
  }
  B1[(size_t)row * 64 + ln] = word;
}

// ---------- boolean mat-power expansion: dst_row = OR_{m in src_row} base[m] ----------
// Parallel bit extraction (lane scans its own word) + unrolled indexed gather.
#define MAXE 96
__global__ __launch_bounds__(256) void k_expand(const u64* __restrict__ src,
                                                const u64* __restrict__ base,
                                                u64* __restrict__ dst) {
  __shared__ int idxs[4][MAXE];
  __shared__ int cnts[4];
  int wv = threadIdx.x >> 6, ln = threadIdx.x & 63;
  int row = blockIdx.x * 4 + wv;
  if (ln == 0) cnts[wv] = 0;
  __syncthreads();
  u64 w = src[(size_t)row * 64 + ln];    // lane scans its OWN word
  while (w) {
    int b = __builtin_ctzll(w);
    w &= w - 1;
    int p = atomicAdd(&cnts[wv], 1);
    if (p < MAXE) idxs[wv][p] = ln * 64 + b;
  }
  __syncthreads();
  int cnt = cnts[wv] < MAXE ? cnts[wv] : MAXE;
  u64 acc = 0;
  int i = 0;
  for (; i + 4 <= cnt; i += 4) {         // 4 independent 512B gathers in flight
    u64 a0 = base[(size_t)idxs[wv][i] * 64 + ln];
    u64 a1 = base[(size_t)idxs[wv][i + 1] * 64 + ln];
    u64 a2 = base[(size_t)idxs[wv][i + 2] * 64 + ln];
    u64 a3 = base[(size_t)idxs[wv][i + 3] * 64 + ln];
    acc |= a0 | a1 | a2 | a3;
  }
  for (; i < cnt; ++i) acc |= base[(size_t)idxs[wv][i] * 64 + ln];
  dst[(size_t)row * 64 + ln] = acc;
}

// ---------- split f32 [R,256] -> bf16 [R,768] hi/lo concat ----------
// pat=1 (A-operand): (hi, lo, hi);  pat=0 (B-operand): (hi, hi, lo)
__global__ __launch_bounds__(256) void k_split(const float* __restrict__ src,
                                               u16* __restrict__ dst, int pat) {
  int rrow = blockIdx.x, c = threadIdx.x;
  float x = src[(size_t)rrow * 256 + c];
  u16 hi = f2bf(x);
  u16 lo = f2bf(x - bf2f(hi));
  size_t b = (size_t)rrow * 768 + c;
  dst[b] = hi;
  dst[b + 256] = pat ? lo : hi;
  dst[b + 512] = pat ? hi : lo;
}

// ---------- transpose+split both weights [256,256] -> [256,768] (B-pattern) ----------
__global__ __launch_bounds__(256) void k_splitT2(const float* __restrict__ W0,
                                                 const float* __restrict__ W1,
                                                 u16* __restrict__ d0,
                                                 u16* __restrict__ d1) {
  int blk = blockIdx.x;
  const float* W = blk < 256 ? W0 : W1;
  u16* dst = blk < 256 ? d0 : d1;
  int n = blk & 255, k = threadIdx.x;
  float x = W[(size_t)k * 256 + n];
  u16 hi = f2bf(x);
  u16 lo = f2bf(x - bf2f(hi));
  size_t b = (size_t)n * 768 + k;
  dst[b] = hi;
  dst[b + 256] = hi;
  dst[b + 512] = lo;
}

// ---------- m97-style NT GEMM: C[M,N] f32 = A[M,K]bf16 * B[N,K]bf16^T ----------
// grid: (N/128, M/128, Z);  Z = split-K partitions, C has Z stacked outputs
__global__ __launch_bounds__(256) void gemm_nt(const u16* __restrict__ A,
                                               const u16* __restrict__ B,
                                               float* __restrict__ C,
                                               int M, int N, int K) {
  __shared__ __align__(16) u16 sA[128 * 32];
  __shared__ __align__(16) u16 sB[128 * 32];
  const int tid = threadIdx.x;
  const int wave = tid >> 6, lane = tid & 63;
  const int wr = wave >> 1, wc = wave & 1;

  // T1: bijective XCD-chunked swizzle (z==1 grids only; nwg%8==0 for all our z==1 grids)
  int bx = blockIdx.x, by = blockIdx.y;
  {
    int nwg = gridDim.x * gridDim.y;
    if (gridDim.z == 1 && (nwg & 7) == 0) {
      int bid = by * gridDim.x + bx;
      int cpx = nwg >> 3;
      bid = (bid & 7) * cpx + (bid >> 3);
      bx = bid % gridDim.x;
      by = bid / gridDim.x;
    }
  }

  const int rowBase = by * 128;
  const int colBase = bx * 128;
  const int kchunk = K / gridDim.z;
  const int k0 = blockIdx.z * kchunk;
  float* Cp = C + (size_t)blockIdx.z * M * N;

  const int srow = lane >> 2;          // row within 16-row staging chunk
  const int skoff = (lane & 3) * 8;    // k element offset for this lane
  const int fr = lane & 15;
  const int fk = (lane >> 4) * 8;

  f32x4 acc[4][4] = {};

  for (int kt = k0; kt < k0 + kchunk; kt += 32) {
    for (int c = wave; c < 8; c += 4) {
      const u16* ga = A + (size_t)(rowBase + c * 16 + srow) * K + kt + skoff;
      gload_lds16(ga, &sA[c * 512]);
      const u16* gb = B + (size_t)(colBase + c * 16 + srow) * K + kt + skoff;
      gload_lds16(gb, &sB[c * 512]);
    }
    __syncthreads();
    bf16x8 af[4], bfr[4];
#pragma unroll
    for (int m = 0; m < 4; ++m)
      af[m] = *(const bf16x8*)&sA[(wr * 64 + m * 16 + fr) * 32 + fk];
#pragma unroll
    for (int n = 0; n < 4; ++n)
      bfr[n] = *(const bf16x8*)&sB[(wc * 64 + n * 16 + fr) * 32 + fk];
#pragma unroll
    for (int m = 0; m < 4; ++m)
#pragma unroll
      for (int n = 0; n < 4; ++n)
        acc[m][n] = __builtin_amdgcn_mfma_f32_16x16x32_bf16(af[m], bfr[n], acc[m][n], 0, 0, 0);
    __syncthreads();
  }
#pragma unroll
  for (int m = 0; m < 4; ++m)
#pragma unroll
    for (int n = 0; n < 4; ++n) {
      int r0 = rowBase + wr * 64 + m * 16 + (lane >> 4) * 4;
      int c0 = colBase + wc * 64 + n * 16 + fr;
#pragma unroll
      for (int r = 0; r < 4; ++r)
        Cp[(size_t)(r0 + r) * N + c0] = acc[m][n][r];
    }
}

// ---------- s_i, s_j ----------
__global__ __launch_bounds__(256) void k_sisj(const float* __restrict__ Wh,
                                              const float* __restrict__ r,
                                              float* __restrict__ s) {
  int wv = threadIdx.x >> 6, ln = threadIdx.x & 63;
  int row = blockIdx.x * 4 + wv;
  const float4 wh = *(const float4*)&Wh[(size_t)row * 256 + ln * 4];
  const float4 ri = *(const float4*)&r[ln * 4];
  const float4 rj = *(const float4*)&r[256 + ln * 4];
  float pi = wh.x * ri.x + wh.y * ri.y + wh.z * ri.z + wh.w * ri.w;
  float pj = wh.x * rj.x + wh.y * rj.y + wh.z * rj.z + wh.w * rj.w;
  for (int o = 32; o; o >>= 1) { pi += __shfl_xor(pi, o); pj += __shfl_xor(pj, o); }
  if (ln == 0) { s[row] = pi; s[NN + row] = pj; }
}

// ---------- phase-1 sparse GAT attention + gelu (wave per row) ----------
#define MAXD 128
__global__ __launch_bounds__(256) void k_attn1(const u64* __restrict__ B1,
                                               const float* __restrict__ s,
                                               const float* __restrict__ Wh,
                                               float* __restrict__ h) {
  __shared__ int idxs[4][MAXD];
  __shared__ float ww[4][MAXD];
  __shared__ int cnts[4];
  int wv = threadIdx.x >> 6, ln = threadIdx.x & 63;
  int row = blockIdx.x * 4 + wv;
  if (ln == 0) cnts[wv] = 0;
  __syncthreads();
  u64 w = B1[(size_t)row * 64 + ln];
  while (w) {
    int b = __builtin_ctzll(w);
    w &= w - 1;
    int p = atomicAdd(&cnts[wv], 1);
    if (p < MAXD) idxs[wv][p] = ln * 64 + b;
  }
  __syncthreads();
  int cnt = cnts[wv] < MAXD ? cnts[wv] : MAXD;
  float si = s[row];
  for (int i = ln; i < cnt; i += 64) {
    float v = si + s[NN + idxs[wv][i]];
    ww[wv][i] = v > 0.f ? v : 0.2f * v;     // leaky_relu
  }
  __syncthreads();
  float mx = -1e30f;
  for (int i = ln; i < cnt; i += 64) mx = fmaxf(mx, ww[wv][i]);
  for (int o = 32; o; o >>= 1) mx = fmaxf(mx, __shfl_xor(mx, o));
  float sm = 0.f;
  for (int i = ln; i < cnt; i += 64) sm += __expf(ww[wv][i] - mx);
  for (int o = 32; o; o >>= 1) sm += __shfl_xor(sm, o);
  float inv = 1.0f / sm;
  for (int i = ln; i < cnt; i += 64) ww[wv][i] = __expf(ww[wv][i] - mx) * inv;
  __syncthreads();
  float a0 = 0, a1 = 0, a2 = 0, a3 = 0;
  for (int t = 0; t < cnt; ++t) {
    float wgt = ww[wv][t];
    const float4 v = *(const float4*)&Wh[(size_t)idxs[wv][t] * 256 + ln * 4];
    a0 = fmaf(wgt, v.x, a0); a1 = fmaf(wgt, v.y, a1);
    a2 = fmaf(wgt, v.z, a2); a3 = fmaf(wgt, v.w, a3);
  }
  float4 o4;
  o4.x = gelu_f(a0); o4.y = gelu_f(a1); o4.z = gelu_f(a2); o4.w = gelu_f(a3);
  *(float4*)&h[(size_t)row * 256 + ln * 4] = o4;
}

// ---------- h [4096,256] f32 -> hT [256,4096] bf16 ----------
__global__ __launch_bounds__(256) void k_transpose(const float* __restrict__ h,
                                                   u16* __restrict__ hT) {
  __shared__ u16 tile[64][65];
  int t = threadIdx.x;
  int bx = blockIdx.x & 3;        // col block of h (256/64)
  int by = blockIdx.x >> 2;       // row block of h (4096/64)
  for (int rr = (t >> 6); rr < 64; rr += 4)
    tile[rr][t & 63] = f2bf(h[(size_t)(by * 64 + rr) * 256 + bx * 64 + (t & 63)]);
  __syncthreads();
  for (int jj = (t >> 6); jj < 64; jj += 4)
    hT[(size_t)(bx * 64 + jj) * NN + by * 64 + (t & 63)] = tile[t & 63][jj];
}

// ---------- combined 3-hop softmax weights: Wc = w1+w2+w3 ----------
// Register-resident: thread t owns columns c(g,j) = g*1024 + 4t + j.
// Tier-3 dense via per-lane nibble mask tests; tier-1/2 (avg ~93 cols/row)
// sparse on wave 0 with their own maxes. Pass C writes ALL columns; sparse
// pass overwrites tier-1/2 columns after a barrier (drains vmcnt).
__global__ __launch_bounds__(256) void k_wc(const float* __restrict__ scores,
                                            const u64* __restrict__ B1,
                                            const u64* __restrict__ B2,
                                            const u64* __restrict__ B3,
                                            u16* __restrict__ Wc) {
  __shared__ u64 sm3[64];
  __shared__ float rmax[4], rsum[4];
  const int t = threadIdx.x;
  const int wv = t >> 6, ln = t & 63;
  const int row = blockIdx.x;
  const size_t rbase = (size_t)row * NN;

  if (t < 64) sm3[t] = B3[(size_t)row * 64 + t];
  // dense register load: 4x dwordx4, 1KB per wave per load
  f32x4 v[4];
  const f32x4* sp = (const f32x4*)(scores + rbase);
#pragma unroll
  for (int g = 0; g < 4; ++g) v[g] = sp[g * 256 + t];
  // wave0 sparse tier masks (per-lane word)
  u64 w2 = 0, w1 = 0;
  if (wv == 0) {
    w2 = B2[(size_t)row * 64 + ln];
    w1 = B1[(size_t)row * 64 + ln];
  }
  __syncthreads();

  const int wi = t >> 4;            // mask word sub-index (per 1024-col group)
  const int sb = (t & 15) * 4;      // bit base within word (j-invariant)
  u32 nib[4];
  float mx3 = -3e38f;
#pragma unroll
  for (int g = 0; g < 4; ++g) {
    u64 wrd = sm3[g * 16 + wi];
    u32 half = (sb < 32) ? (u32)wrd : (u32)(wrd >> 32);
    nib[g] = (half >> (sb & 31)) & 0xFu;
#pragma unroll
    for (int j = 0; j < 4; ++j)
      if (nib[g] & (1u << j)) mx3 = fmaxf(mx3, v[g][j]);
  }
  for (int o = 32; o; o >>= 1) mx3 = fmaxf(mx3, __shfl_xor(mx3, o));
  if (ln == 0) rmax[wv] = mx3;

  // wave0: sparse tier-2/1 maxes (scores row is L1/L2-hot)
  float mx2 = -3e38f, mx1 = -3e38f;
  if (wv == 0) {
    u64 w = w2;
    while (w) {
      int b = __builtin_ctzll(w); w &= w - 1;
      float sc = scores[rbase + ln * 64 + b];
      mx2 = fmaxf(mx2, sc);
      if (w1 & (1ull << b)) mx1 = fmaxf(mx1, sc);
    }
    for (int o = 32; o; o >>= 1) {
      mx2 = fmaxf(mx2, __shfl_xor(mx2, o));
      mx1 = fmaxf(mx1, __shfl_xor(mx1, o));
    }
  }
  __syncthreads();
  mx3 = fmaxf(fmaxf(rmax[0], rmax[1]), fmaxf(rmax[2], rmax[3]));

  // pass B: e = exp(v - mx3) masked; overwrite regs; accumulate s3
  float s3 = 0.f;
#pragma unroll
  for (int g = 0; g < 4; ++g)
#pragma unroll
    for (int j = 0; j < 4; ++j) {
      float e = __expf(v[g][j] - mx3);
      e = (nib[g] & (1u << j)) ? e : 0.f;
      v[g][j] = e;
      s3 += e;
    }
  for (int o = 32; o; o >>= 1) s3 += __shfl_xor(s3, o);
  if (ln == 0) rsum[wv] = s3;

  // wave0: sparse tier-2/1 sums
  float s2 = 1.f, s1 = 1.f;
  if (wv == 0) {
    float s2p = 0.f, s1p = 0.f;
    u64 w = w2;
    while (w) {
      int b = __builtin_ctzll(w); w &= w - 1;
      float sc = scores[rbase + ln * 64 + b];
      s2p += __expf(sc - mx2);
      if (w1 & (1ull << b)) s1p += __expf(sc - mx1);
    }
    for (int o = 32; o; o >>= 1) {
      s2p += __shfl_xor(s2p, o);
      s1p += __shfl_xor(s1p, o);
    }
    s2 = s2p; s1 = s1p;
  }
  __syncthreads();
  s3 = rsum[0] + rsum[1] + rsum[2] + rsum[3];
  float inv3 = 1.0f / s3;

  // pass C: write all columns (tier-3 weight; 0 outside mask3)
#pragma unroll
  for (int g = 0; g < 4; ++g) {
    u16 o0 = f2bf(v[g][0] * inv3), o1 = f2bf(v[g][1] * inv3);
    u16 o2 = f2bf(v[g][2] * inv3), o3 = f2bf(v[g][3] * inv3);
    uint2 pk;
    pk.x = (u32)o0 | ((u32)o1 << 16);
    pk.y = (u32)o2 | ((u32)o3 << 16);
    *(uint2*)&Wc[rbase + (size_t)g * 1024 + t * 4] = pk;
  }
  __syncthreads();   // pass-C stores drained before sparse overwrite

  // wave0: overwrite tier-2/1 columns with full combined weight
  if (wv == 0) {
    float inv2 = 1.0f / s2, inv1 = 1.0f / s1;
    u64 w = w2;
    while (w) {
      int b = __builtin_ctzll(w); w &= w - 1;
      int c = ln * 64 + b;
      float sc = scores[rbase + c];
      float wgt = __expf(sc - mx3) * inv3 + __expf(sc - mx2) * inv2;
      if (w1 & (1ull << b)) wgt += __expf(sc - mx1) * inv1;
      Wc[rbase + c] = f2bf(wgt);
    }
  }
}

// ---------- final: out = (h + sum tmp_z) @ W_out + b_out ----------
__global__ __launch_bounds__(128) void k_final(const float* __restrict__ h,
                                               const float* __restrict__ tmp,
                                               const float* __restrict__ Wout,
                                               const float* __restrict__ bout,
                                               float* __restrict__ out) {
  __shared__ float rrow[8][256];
  int t = threadIdx.x;
  int row0 = blockIdx.x * 8;
  const size_t P = (size_t)NN * 256;
  for (int i = t; i < 8 * 256; i += 128) {
    int rr = i >> 8, k = i & 255;
    size_t idx = (size_t)(row0 + rr) * 256 + k;
    rrow[rr][k] = h[idx] + tmp[idx] + tmp[idx + P] + tmp[idx + 2 * P] + tmp[idx + 3 * P];
  }
  __syncthreads();
  float b = bout[t];
  float acc[8];
#pragma unroll
  for (int i = 0; i < 8; ++i) acc[i] = b;
  for (int k = 0; k < 256; ++k) {
    float w = Wout[k * 128 + t];
#pragma unroll
    for (int i = 0; i < 8; ++i) acc[i] = fmaf(rrow[i][k], w, acc[i]);
  }
#pragma unroll
  for (int i = 0; i < 8; ++i) out[(size_t)(row0 + i) * 128 + t] = acc[i];
}

// ---------- host ----------
extern "C" void kernel_launch(void* const* d_in, const int* in_sizes, int n_in,
                              void* d_out, int out_size, void* d_ws, size_t ws_size,
                              hipStream_t stream) {
  const float* X    = (const float*)d_in[0];
  const float* A    = (const float*)d_in[1];
  const float* W_s  = (const float*)d_in[2];
  const float* r    = (const float*)d_in[3];
  const float* W_l  = (const float*)d_in[4];
  const float* Wout = (const float*)d_in[5];
  const float* bout = (const float*)d_in[6];
  float* out = (float*)d_out;

  char* wp = (char*)d_ws;
  auto take = [&](size_t n) { char* p = wp; wp += (n + 255) & ~(size_t)255; return p; };
  u64* B1     = (u64*)take((size_t)NN * 64 * 8);      // 2 MB
  u64* B2     = (u64*)take((size_t)NN * 64 * 8);      // 2 MB
  u64* B3     = (u64*)take((size_t)NN * 64 * 8);      // 2 MB
  float* Wh   = (float*)take((size_t)NN * 256 * 4);   // 4 MB
  float* sv   = (float*)take((size_t)2 * NN * 4);     // 32 KB
  float* h    = (float*)take((size_t)NN * 256 * 4);   // 4 MB
  u16* hT     = (u16*)take((size_t)256 * NN * 2);     // 2 MB
  u16* hsp    = (u16*)take((size_t)NN * 768 * 2);     // 6 MB
  u16* Wasp   = (u16*)take((size_t)NN * 768 * 2);     // 6 MB
  u16* Xsp    = (u16*)take((size_t)NN * 768 * 2);     // 6 MB (reused as Wa f32)
  float* Wa   = (float*)Xsp;                          // alias: Xsp dead after Wh GEMM
  u16* WsT    = (u16*)take((size_t)256 * 768 * 2);
  u16* WlT    = (u16*)take((size_t)256 * 768 * 2);
  float* scores = (float*)take((size_t)NN * NN * 4);  // 64 MB (reused as tmp 16 MB)
  float* tmp  = scores;                               // alias: scores dead after k_wc
  u16* Wc     = (u16*)take((size_t)NN * NN * 2);      // 32 MB
  (void)n_in; (void)in_sizes; (void)out_size; (void)ws_size;

  // masks
  k_bitset<<<NN / 4, 256, 0, stream>>>(A, B1);
  k_expand<<<NN / 4, 256, 0, stream>>>(B1, B1, B2);
  k_expand<<<NN / 4, 256, 0, stream>>>(B1, B2, B3);   // B3 = B1*B2 (boolean powers commute)
  // weight prep (both transposed splits in one launch)
  k_splitT2<<<512, 256, 0, stream>>>(W_s, W_l, WsT, WlT);
  k_split<<<NN, 256, 0, stream>>>(X, Xsp, 1);
  // Wh = X @ W_s   (split-bf16, K=768)
  gemm_nt<<<dim3(2, 32, 1), 256, 0, stream>>>(Xsp, WsT, Wh, NN, 256, 768);
  k_sisj<<<NN / 4, 256, 0, stream>>>(Wh, r, sv);
  k_attn1<<<NN / 4, 256, 0, stream>>>(B1, sv, Wh, h);
  k_split<<<NN, 256, 0, stream>>>(h, hsp, 1);
  k_transpose<<<256, 256, 0, stream>>>(h, hT);
  // Wa = h @ W_l
  gemm_nt<<<dim3(2, 32, 1), 256, 0, stream>>>(hsp, WlT, Wa, NN, 256, 768);
  k_split<<<NN, 256, 0, stream>>>(Wa, Wasp, 0);
  // scores = h @ Wa^T  (split-bf16, near-f32)
  gemm_nt<<<dim3(32, 32, 1), 256, 0, stream>>>(hsp, Wasp, scores, NN, NN, 768);
  // combined 3-hop softmax weights
  k_wc<<<NN, 256, 0, stream>>>(scores, B1, B2, B3, Wc);
  // tmp = Wc @ h   (split-K=4 over K=4096)
  gemm_nt<<<dim3(2, 32, 4), 256, 0, stream>>>(Wc, hT, tmp, NN, 256, NN);
  // out = (h + tmp) @ W_out + b_out
  k_final<<<NN / 8, 128, 0, stream>>>(h, tmp, Wout, bout, out);
}

// Round 10
// 289.475 us; speedup vs baseline: 1.3871x; 1.0386x over previous
//
#include <hip/hip_runtime.h>
#include <cstdint>
#include <cstddef>

typedef unsigned long long u64;
typedef unsigned short u16;
typedef unsigned int u32;
typedef __bf16 bf16x8 __attribute__((ext_vector_type(8)));
typedef float f32x4 __attribute__((ext_vector_type(4)));

#define NN 4096
#define HIDD 256

// ---------- helpers ----------
__device__ __forceinline__ u16 f2bf(float f) {
  unsigned int u = __float_as_uint(f);
  u = u + 0x7FFFu + ((u >> 16) & 1u);   // RNE
  return (u16)(u >> 16);
}
__device__ __forceinline__ float bf2f(u16 h) {
  return __uint_as_float(((unsigned int)h) << 16);
}
__device__ __forceinline__ float gelu_f(float x) {
  return 0.5f * x * (1.0f + erff(x * 0.70710678118654752f));
}
__device__ __forceinline__ void gload_lds16(const u16* g, u16* l) {
  __builtin_amdgcn_global_load_lds((const __attribute__((address_space(1))) void*)g,
                                   (__attribute__((address_space(3))) void*)l, 16, 0, 0);
}

// ---------- K0: adjacency -> bitset rows (float4 loads + nibble LDS assembly) ----------
__global__ __launch_bounds__(256) void k_bitset(const float* __restrict__ A, u64* __restrict__ B1) {
  __shared__ unsigned char nib[4][1024];
  int wv = threadIdx.x >> 6, ln = threadIdx.x & 63;
  int row = blockIdx.x * 4 + wv;
  const float4* ar = (const float4*)(A + (size_t)row * NN);
#pragma unroll
  for (int it = 0; it < 16; ++it) {
    float4 v = ar[it * 64 + ln];
    unsigned n = (v.x != 0.f ? 1u : 0u) | (v.y != 0.f ? 2u : 0u) |
                 (v.z != 0.f ? 4u : 0u) | (v.w != 0.f ? 8u : 0u);
    nib[wv][it * 64 + ln] = (unsigned char)n;
  }
  __syncthreads();
  const u32* np4 = (const u32*)&nib[wv][ln * 16];
  u64 word = 0;
#pragma unroll
  for (int q = 0; q < 4; ++q) {
    u32 four = np4[q];
    u64 part = (u64)(four & 0xFu) | ((u64)((four >> 8) & 0xFu) << 4) |
               ((u64)((four >> 16) & 0xFu) << 8) | ((u64)((four >> 24) & 0xFu) << 12);
    word |= part << (16 * q);
  }
  B1[(size_t)row * 64 + ln] = word;
}

// ---------- boolean mat-power expansion: dst_row = OR_{m in src_row} base[m] ----------
#define MAXE 96
__global__ __launch_bounds__(256) void k_expand(const u64* __restrict__ src,
                                                const u64* __restrict__ base,
                                                u64* __restrict__ dst) {
  __shared__ int idxs[4][MAXE];
  __shared__ int cnts[4];
  int wv = threadIdx.x >> 6, ln = threadIdx.x & 63;
  int row = blockIdx.x * 4 + wv;
  if (ln == 0) cnts[wv] = 0;
  __syncthreads();
  u64 w = src[(size_t)row * 64 + ln];
  while (w) {
    int b = __builtin_ctzll(w);
    w &= w - 1;
    int p = atomicAdd(&cnts[wv], 1);
    if (p < MAXE) idxs[wv][p] = ln * 64 + b;
  }
  __syncthreads();
  int cnt = cnts[wv] < MAXE ? cnts[wv] : MAXE;
  u64 acc = 0;
  int i = 0;
  for (; i + 4 <= cnt; i += 4) {
    u64 a0 = base[(size_t)idxs[wv][i] * 64 + ln];
    u64 a1 = base[(size_t)idxs[wv][i + 1] * 64 + ln];
    u64 a2 = base[(size_t)idxs[wv][i + 2] * 64 + ln];
    u64 a3 = base[(size_t)idxs[wv][i + 3] * 64 + ln];
    acc |= a0 | a1 | a2 | a3;
  }
  for (; i < cnt; ++i) acc |= base[(size_t)idxs[wv][i] * 64 + ln];
  dst[(size_t)row * 64 + ln] = acc;
}

// ---------- split f32 [R,256] -> bf16 [R,768] hi/lo concat ----------
__global__ __launch_bounds__(256) void k_split(const float* __restrict__ src,
                                               u16* __restrict__ dst, int pat) {
  int rrow = blockIdx.x, c = threadIdx.x;
  float x = src[(size_t)rrow * 256 + c];
  u16 hi = f2bf(x);
  u16 lo = f2bf(x - bf2f(hi));
  size_t b = (size_t)rrow * 768 + c;
  dst[b] = hi;
  dst[b + 256] = pat ? lo : hi;
  dst[b + 512] = pat ? hi : lo;
}

// ---------- sum 2 split-K partials then split (B-pattern hi,hi,lo) ----------
__global__ __launch_bounds__(256) void k_split_r2(const float* __restrict__ p,
                                                  u16* __restrict__ dst) {
  int rrow = blockIdx.x, c = threadIdx.x;
  size_t idx = (size_t)rrow * 256 + c;
  const size_t P = (size_t)NN * 256;
  float x = p[idx] + p[idx + P];
  u16 hi = f2bf(x);
  u16 lo = f2bf(x - bf2f(hi));
  size_t b = (size_t)rrow * 768 + c;
  dst[b] = hi;
  dst[b + 256] = hi;
  dst[b + 512] = lo;
}

// ---------- sum 2 split-K partials (float4) ----------
__global__ __launch_bounds__(256) void k_reduce2(const float* __restrict__ p,
                                                 float* __restrict__ dst) {
  const size_t P4 = (size_t)NN * 64;   // float4 units per partial
  size_t i = (size_t)blockIdx.x * 256 + threadIdx.x;
  const f32x4* a = (const f32x4*)p;
  f32x4 v = a[i];
  f32x4 w = a[i + P4];
  v[0] += w[0]; v[1] += w[1]; v[2] += w[2]; v[3] += w[3];
  ((f32x4*)dst)[i] = v;
}

// ---------- transpose+split both weights [256,256] -> [256,768] (B-pattern) ----------
__global__ __launch_bounds__(256) void k_splitT2(const float* __restrict__ W0,
                                                 const float* __restrict__ W1,
                                                 u16* __restrict__ d0,
                                                 u16* __restrict__ d1) {
  int blk = blockIdx.x;
  const float* W = blk < 256 ? W0 : W1;
  u16* dst = blk < 256 ? d0 : d1;
  int n = blk & 255, k = threadIdx.x;
  float x = W[(size_t)k * 256 + n];
  u16 hi = f2bf(x);
  u16 lo = f2bf(x - bf2f(hi));
  size_t b = (size_t)n * 768 + k;
  dst[b] = hi;
  dst[b + 256] = hi;
  dst[b + 512] = lo;
}

// ---------- m97-style NT GEMM 128x128: C[M,N] f32 = A[M,K]bf16 * B[N,K]^T ----------
__global__ __launch_bounds__(256) void gemm_nt(const u16* __restrict__ A,
                                               const u16* __restrict__ B,
                                               float* __restrict__ C,
                                               int M, int N, int K) {
  __shared__ __align__(16) u16 sA[128 * 32];
  __shared__ __align__(16) u16 sB[128 * 32];
  const int tid = threadIdx.x;
  const int wave = tid >> 6, lane = tid & 63;
  const int wr = wave >> 1, wc = wave & 1;

  int bx = blockIdx.x, by = blockIdx.y;
  {
    int nwg = gridDim.x * gridDim.y;
    if (gridDim.z == 1 && (nwg & 7) == 0) {
      int bid = by * gridDim.x + bx;
      int cpx = nwg >> 3;
      bid = (bid & 7) * cpx + (bid >> 3);
      bx = bid % gridDim.x;
      by = bid / gridDim.x;
    }
  }

  const int rowBase = by * 128;
  const int colBase = bx * 128;
  const int kchunk = K / gridDim.z;
  const int k0 = blockIdx.z * kchunk;
  float* Cp = C + (size_t)blockIdx.z * M * N;

  const int srow = lane >> 2;
  const int skoff = (lane & 3) * 8;
  const int fr = lane & 15;
  const int fk = (lane >> 4) * 8;

  f32x4 acc[4][4] = {};

  for (int kt = k0; kt < k0 + kchunk; kt += 32) {
    for (int c = wave; c < 8; c += 4) {
      const u16* ga = A + (size_t)(rowBase + c * 16 + srow) * K + kt + skoff;
      gload_lds16(ga, &sA[c * 512]);
      const u16* gb = B + (size_t)(colBase + c * 16 + srow) * K + kt + skoff;
      gload_lds16(gb, &sB[c * 512]);
    }
    __syncthreads();
    bf16x8 af[4], bfr[4];
#pragma unroll
    for (int m = 0; m < 4; ++m)
      af[m] = *(const bf16x8*)&sA[(wr * 64 + m * 16 + fr) * 32 + fk];
#pragma unroll
    for (int n = 0; n < 4; ++n)
      bfr[n] = *(const bf16x8*)&sB[(wc * 64 + n * 16 + fr) * 32 + fk];
#pragma unroll
    for (int m = 0; m < 4; ++m)
#pragma unroll
      for (int n = 0; n < 4; ++n)
        acc[m][n] = __builtin_amdgcn_mfma_f32_16x16x32_bf16(af[m], bfr[n], acc[m][n], 0, 0, 0);
    __syncthreads();
  }
#pragma unroll
  for (int m = 0; m < 4; ++m)
#pragma unroll
    for (int n = 0; n < 4; ++n) {
      int r0 = rowBase + wr * 64 + m * 16 + (lane >> 4) * 4;
      int c0 = colBase + wc * 64 + n * 16 + fr;
#pragma unroll
      for (int r = 0; r < 4; ++r)
        Cp[(size_t)(r0 + r) * N + c0] = acc[m][n][r];
    }
}

// ---------- 64x64-tile NT GEMM for narrow N (high grid parallelism) ----------
// grid: (N/64, M/64, Z); 4 waves; wave w: rows 32*(w>>1), cols 32*(w&1)
__global__ __launch_bounds__(256) void gemm64_nt(const u16* __restrict__ A,
                                                 const u16* __restrict__ B,
                                                 float* __restrict__ C,
                                                 int M, int N, int K) {
  __shared__ __align__(16) u16 sA[64 * 32];
  __shared__ __align__(16) u16 sB[64 * 32];
  const int tid = threadIdx.x;
  const int wave = tid >> 6, lane = tid & 63;
  const int wr = wave >> 1, wc = wave & 1;
  const int rowBase = blockIdx.y * 64;
  const int colBase = blockIdx.x * 64;
  const int kchunk = K / gridDim.z;
  const int k0 = blockIdx.z * kchunk;
  float* Cp = C + (size_t)blockIdx.z * M * N;

  const int srow = lane >> 2;          // wave stages rows 16*wave .. +15
  const int skoff = (lane & 3) * 8;
  const int fr = lane & 15;
  const int fk = (lane >> 4) * 8;

  f32x4 acc[2][2] = {};

  for (int kt = k0; kt < k0 + kchunk; kt += 32) {
    const u16* ga = A + (size_t)(rowBase + wave * 16 + srow) * K + kt + skoff;
    gload_lds16(ga, &sA[wave * 512]);
    const u16* gb = B + (size_t)(colBase + wave * 16 + srow) * K + kt + skoff;
    gload_lds16(gb, &sB[wave * 512]);
    __syncthreads();
    bf16x8 af[2], bfr[2];
#pragma unroll
    for (int m = 0; m < 2; ++m)
      af[m] = *(const bf16x8*)&sA[(wr * 32 + m * 16 + fr) * 32 + fk];
#pragma unroll
    for (int n = 0; n < 2; ++n)
      bfr[n] = *(const bf16x8*)&sB[(wc * 32 + n * 16 + fr) * 32 + fk];
#pragma unroll
    for (int m = 0; m < 2; ++m)
#pragma unroll
      for (int n = 0; n < 2; ++n)
        acc[m][n] = __builtin_amdgcn_mfma_f32_16x16x32_bf16(af[m], bfr[n], acc[m][n], 0, 0, 0);
    __syncthreads();
  }
#pragma unroll
  for (int m = 0; m < 2; ++m)
#pragma unroll
    for (int n = 0; n < 2; ++n) {
      int r0 = rowBase + wr * 32 + m * 16 + (lane >> 4) * 4;
      int c0 = colBase + wc * 32 + n * 16 + fr;
#pragma unroll
      for (int r = 0; r < 4; ++r)
        Cp[(size_t)(r0 + r) * N + c0] = acc[m][n][r];
    }
}

// ---------- s_i, s_j ----------
__global__ __launch_bounds__(256) void k_sisj(const float* __restrict__ Wh,
                                              const float* __restrict__ r,
                                              float* __restrict__ s) {
  int wv = threadIdx.x >> 6, ln = threadIdx.x & 63;
  int row = blockIdx.x * 4 + wv;
  const float4 wh = *(const float4*)&Wh[(size_t)row * 256 + ln * 4];
  const float4 ri = *(const float4*)&r[ln * 4];
  const float4 rj = *(const float4*)&r[256 + ln * 4];
  float pi = wh.x * ri.x + wh.y * ri.y + wh.z * ri.z + wh.w * ri.w;
  float pj = wh.x * rj.x + wh.y * rj.y + wh.z * rj.z + wh.w * rj.w;
  for (int o = 32; o; o >>= 1) { pi += __shfl_xor(pi, o); pj += __shfl_xor(pj, o); }
  if (ln == 0) { s[row] = pi; s[NN + row] = pj; }
}

// ---------- phase-1 sparse GAT attention + gelu (wave per row) ----------
#define MAXD 128
__global__ __launch_bounds__(256) void k_attn1(const u64* __restrict__ B1,
                                               const float* __restrict__ s,
                                               const float* __restrict__ Wh,
                                               float* __restrict__ h) {
  __shared__ int idxs[4][MAXD];
  __shared__ float ww[4][MAXD];
  __shared__ int cnts[4];
  int wv = threadIdx.x >> 6, ln = threadIdx.x & 63;
  int row = blockIdx.x * 4 + wv;
  if (ln == 0) cnts[wv] = 0;
  __syncthreads();
  u64 w = B1[(size_t)row * 64 + ln];
  while (w) {
    int b = __builtin_ctzll(w);
    w &= w - 1;
    int p = atomicAdd(&cnts[wv], 1);
    if (p < MAXD) idxs[wv][p] = ln * 64 + b;
  }
  __syncthreads();
  int cnt = cnts[wv] < MAXD ? cnts[wv] : MAXD;
  float si = s[row];
  for (int i = ln; i < cnt; i += 64) {
    float v = si + s[NN + idxs[wv][i]];
    ww[wv][i] = v > 0.f ? v : 0.2f * v;
  }
  __syncthreads();
  float mx = -1e30f;
  for (int i = ln; i < cnt; i += 64) mx = fmaxf(mx, ww[wv][i]);
  for (int o = 32; o; o >>= 1) mx = fmaxf(mx, __shfl_xor(mx, o));
  float sm = 0.f;
  for (int i = ln; i < cnt; i += 64) sm += __expf(ww[wv][i] - mx);
  for (int o = 32; o; o >>= 1) sm += __shfl_xor(sm, o);
  float inv = 1.0f / sm;
  for (int i = ln; i < cnt; i += 64) ww[wv][i] = __expf(ww[wv][i] - mx) * inv;
  __syncthreads();
  float a0 = 0, a1 = 0, a2 = 0, a3 = 0;
  for (int t = 0; t < cnt; ++t) {
    float wgt = ww[wv][t];
    const float4 v = *(const float4*)&Wh[(size_t)idxs[wv][t] * 256 + ln * 4];
    a0 = fmaf(wgt, v.x, a0); a1 = fmaf(wgt, v.y, a1);
    a2 = fmaf(wgt, v.z, a2); a3 = fmaf(wgt, v.w, a3);
  }
  float4 o4;
  o4.x = gelu_f(a0); o4.y = gelu_f(a1); o4.z = gelu_f(a2); o4.w = gelu_f(a3);
  *(float4*)&h[(size_t)row * 256 + ln * 4] = o4;
}

// ---------- h [4096,256] f32 -> hT [256,4096] bf16 ----------
__global__ __launch_bounds__(256) void k_transpose(const float* __restrict__ h,
                                                   u16* __restrict__ hT) {
  __shared__ u16 tile[64][65];
  int t = threadIdx.x;
  int bx = blockIdx.x & 3;
  int by = blockIdx.x >> 2;
  for (int rr = (t >> 6); rr < 64; rr += 4)
    tile[rr][t & 63] = f2bf(h[(size_t)(by * 64 + rr) * 256 + bx * 64 + (t & 63)]);
  __syncthreads();
  for (int jj = (t >> 6); jj < 64; jj += 4)
    hT[(size_t)(bx * 64 + jj) * NN + by * 64 + (t & 63)] = tile[t & 63][jj];
}

// ---------- combined 3-hop softmax weights: Wc = w1+w2+w3 ----------
__global__ __launch_bounds__(256) void k_wc(const float* __restrict__ scores,
                                            const u64* __restrict__ B1,
                                            const u64* __restrict__ B2,
                                            const u64* __restrict__ B3,
                                            u16* __restrict__ Wc) {
  __shared__ u64 sm3[64];
  __shared__ float rmax[4], rsum[4];
  const int t = threadIdx.x;
  const int wv = t >> 6, ln = t & 63;
  const int row = blockIdx.x;
  const size_t rbase = (size_t)row * NN;

  if (t < 64) sm3[t] = B3[(size_t)row * 64 + t];
  f32x4 v[4];
  const f32x4* sp = (const f32x4*)(scores + rbase);
#pragma unroll
  for (int g = 0; g < 4; ++g) v[g] = sp[g * 256 + t];
  u64 w2 = 0, w1 = 0;
  if (wv == 0) {
    w2 = B2[(size_t)row * 64 + ln];
    w1 = B1[(size_t)row * 64 + ln];
  }
  __syncthreads();

  const int wi = t >> 4;
  const int sb = (t & 15) * 4;
  u32 nib[4];
  float mx3 = -3e38f;
#pragma unroll
  for (int g = 0; g < 4; ++g) {
    u64 wrd = sm3[g * 16 + wi];
    u32 half = (sb < 32) ? (u32)wrd : (u32)(wrd >> 32);
    nib[g] = (half >> (sb & 31)) & 0xFu;
#pragma unroll
    for (int j = 0; j < 4; ++j)
      if (nib[g] & (1u << j)) mx3 = fmaxf(mx3, v[g][j]);
  }
  for (int o = 32; o; o >>= 1) mx3 = fmaxf(mx3, __shfl_xor(mx3, o));
  if (ln == 0) rmax[wv] = mx3;

  float mx2 = -3e38f, mx1 = -3e38f;
  if (wv == 0) {
    u64 w = w2;
    while (w) {
      int b = __builtin_ctzll(w); w &= w - 1;
      float sc = scores[rbase + ln * 64 + b];
      mx2 = fmaxf(mx2, sc);
      if (w1 & (1ull << b)) mx1 = fmaxf(mx1, sc);
    }
    for (int o = 32; o; o >>= 1) {
      mx2 = fmaxf(mx2, __shfl_xor(mx2, o));
      mx1 = fmaxf(mx1, __shfl_xor(mx1, o));
    }
  }
  __syncthreads();
  mx3 = fmaxf(fmaxf(rmax[0], rmax[1]), fmaxf(rmax[2], rmax[3]));

  float s3 = 0.f;
#pragma unroll
  for (int g = 0; g < 4; ++g)
#pragma unroll
    for (int j = 0; j < 4; ++j) {
      float e = __expf(v[g][j] - mx3);
      e = (nib[g] & (1u << j)) ? e : 0.f;
      v[g][j] = e;
      s3 += e;
    }
  for (int o = 32; o; o >>= 1) s3 += __shfl_xor(s3, o);
  if (ln == 0) rsum[wv] = s3;

  float s2 = 1.f, s1 = 1.f;
  if (wv == 0) {
    float s2p = 0.f, s1p = 0.f;
    u64 w = w2;
    while (w) {
      int b = __builtin_ctzll(w); w &= w - 1;
      float sc = scores[rbase + ln * 64 + b];
      s2p += __expf(sc - mx2);
      if (w1 & (1ull << b)) s1p += __expf(sc - mx1);
    }
    for (int o = 32; o; o >>= 1) {
      s2p += __shfl_xor(s2p, o);
      s1p += __shfl_xor(s1p, o);
    }
    s2 = s2p; s1 = s1p;
  }
  __syncthreads();
  s3 = rsum[0] + rsum[1] + rsum[2] + rsum[3];
  float inv3 = 1.0f / s3;

#pragma unroll
  for (int g = 0; g < 4; ++g) {
    u16 o0 = f2bf(v[g][0] * inv3), o1 = f2bf(v[g][1] * inv3);
    u16 o2 = f2bf(v[g][2] * inv3), o3 = f2bf(v[g][3] * inv3);
    uint2 pk;
    pk.x = (u32)o0 | ((u32)o1 << 16);
    pk.y = (u32)o2 | ((u32)o3 << 16);
    *(uint2*)&Wc[rbase + (size_t)g * 1024 + t * 4] = pk;
  }
  __syncthreads();

  if (wv == 0) {
    float inv2 = 1.0f / s2, inv1 = 1.0f / s1;
    u64 w = w2;
    while (w) {
      int b = __builtin_ctzll(w); w &= w - 1;
      int c = ln * 64 + b;
      float sc = scores[rbase + c];
      float wgt = __expf(sc - mx3) * inv3 + __expf(sc - mx2) * inv2;
      if (w1 & (1ull << b)) wgt += __expf(sc - mx1) * inv1;
      Wc[rbase + c] = f2bf(wgt);
    }
  }
}

// ---------- final: out = (h + sum tmp_z) @ W_out + b_out ----------
__global__ __launch_bounds__(128) void k_final(const float* __restrict__ h,
                                               const float* __restrict__ tmp,
                                               const float* __restrict__ Wout,
                                               const float* __restrict__ bout,
                                               float* __restrict__ out) {
  __shared__ float rrow[8][256];
  int t = threadIdx.x;
  int row0 = blockIdx.x * 8;
  const size_t P = (size_t)NN * 256;
  for (int i = t; i < 8 * 256; i += 128) {
    int rr = i >> 8, k = i & 255;
    size_t idx = (size_t)(row0 + rr) * 256 + k;
    rrow[rr][k] = h[idx] + tmp[idx] + tmp[idx + P] + tmp[idx + 2 * P] + tmp[idx + 3 * P];
  }
  __syncthreads();
  float b = bout[t];
  float acc[8];
#pragma unroll
  for (int i = 0; i < 8; ++i) acc[i] = b;
  for (int k = 0; k < 256; ++k) {
    float w = Wout[k * 128 + t];
#pragma unroll
    for (int i = 0; i < 8; ++i) acc[i] = fmaf(rrow[i][k], w, acc[i]);
  }
#pragma unroll
  for (int i = 0; i < 8; ++i) out[(size_t)(row0 + i) * 128 + t] = acc[i];
}

// ---------- host ----------
extern "C" void kernel_launch(void* const* d_in, const int* in_sizes, int n_in,
                              void* d_out, int out_size, void* d_ws, size_t ws_size,
                              hipStream_t stream) {
  const float* X    = (const float*)d_in[0];
  const float* A    = (const float*)d_in[1];
  const float* W_s  = (const float*)d_in[2];
  const float* r    = (const float*)d_in[3];
  const float* W_l  = (const float*)d_in[4];
  const float* Wout = (const float*)d_in[5];
  const float* bout = (const float*)d_in[6];
  float* out = (float*)d_out;

  char* wp = (char*)d_ws;
  auto take = [&](size_t n) { char* p = wp; wp += (n + 255) & ~(size_t)255; return p; };
  u64* B1     = (u64*)take((size_t)NN * 64 * 8);      // 2 MB
  u64* B2     = (u64*)take((size_t)NN * 64 * 8);      // 2 MB
  u64* B3     = (u64*)take((size_t)NN * 64 * 8);      // 2 MB
  float* Wh   = (float*)take((size_t)NN * 256 * 4);   // 4 MB
  float* sv   = (float*)take((size_t)2 * NN * 4);     // 32 KB
  float* h    = (float*)take((size_t)NN * 256 * 4);   // 4 MB
  u16* hT     = (u16*)take((size_t)256 * NN * 2);     // 2 MB
  u16* hsp    = (u16*)take((size_t)NN * 768 * 2);     // 6 MB
  u16* Wasp   = (u16*)take((size_t)NN * 768 * 2);     // 6 MB
  u16* Xsp    = (u16*)take((size_t)NN * 768 * 2);     // 6 MB
  u16* WsT    = (u16*)take((size_t)256 * 768 * 2);
  u16* WlT    = (u16*)take((size_t)256 * 768 * 2);
  float* scores = (float*)take((size_t)NN * NN * 4);  // 64 MB; front reused:
  float* Whp  = scores;                               //   2x4MB Wh partials (dead pre-scores)
  float* Wap  = scores + (size_t)2 * NN * 256;        //   2x4MB Wa partials (dead pre-scores)
  float* tmp  = scores;                               //   4x4MB Wc@h partials (post-k_wc)
  u16* Wc     = (u16*)take((size_t)NN * NN * 2);      // 32 MB
  (void)n_in; (void)in_sizes; (void)out_size; (void)ws_size;

  // masks
  k_bitset<<<NN / 4, 256, 0, stream>>>(A, B1);
  k_expand<<<NN / 4, 256, 0, stream>>>(B1, B1, B2);
  k_expand<<<NN / 4, 256, 0, stream>>>(B1, B2, B3);   // B3 = B1*B2
  // weight prep
  k_splitT2<<<512, 256, 0, stream>>>(W_s, W_l, WsT, WlT);
  k_split<<<NN, 256, 0, stream>>>(X, Xsp, 1);
  // Wh = X @ W_s (64-tile, split-K2 -> reduce)
  gemm64_nt<<<dim3(4, 64, 2), 256, 0, stream>>>(Xsp, WsT, Whp, NN, 256, 768);
  k_reduce2<<<1024, 256, 0, stream>>>(Whp, Wh);
  k_sisj<<<NN / 4, 256, 0, stream>>>(Wh, r, sv);
  k_attn1<<<NN / 4, 256, 0, stream>>>(B1, sv, Wh, h);
  k_split<<<NN, 256, 0, stream>>>(h, hsp, 1);
  k_transpose<<<256, 256, 0, stream>>>(h, hT);
  // Wa = h @ W_l (64-tile, split-K2; reduce fused into split)
  gemm64_nt<<<dim3(4, 64, 2), 256, 0, stream>>>(hsp, WlT, Wap, NN, 256, 768);
  k_split_r2<<<NN, 256, 0, stream>>>(Wap, Wasp);
  // scores = h @ Wa^T  (split-bf16, near-f32)
  gemm_nt<<<dim3(32, 32, 1), 256, 0, stream>>>(hsp, Wasp, scores, NN, NN, 768);
  // combined 3-hop softmax weights
  k_wc<<<NN, 256, 0, stream>>>(scores, B1, B2, B3, Wc);
  // tmp = Wc @ h   (64-tile, split-K=4 over K=4096)
  gemm64_nt<<<dim3(4, 64, 4), 256, 0, stream>>>(Wc, hT, tmp, NN, 256, NN);
  // out = (h + tmp) @ W_out + b_out
  k_final<<<NN / 8, 128, 0, stream>>>(h, tmp, Wout, bout, out);
}

// Round 13
// 285.202 us; speedup vs baseline: 1.4079x; 1.0150x over previous
//
#include <hip/hip_runtime.h>
#include <cstdint>
#include <cstddef>

typedef unsigned long long u64;
typedef unsigned short u16;
typedef unsigned int u32;
typedef __bf16 bf16x8 __attribute__((ext_vector_type(8)));
typedef float f32x4 __attribute__((ext_vector_type(4)));

#define NN 4096
#define HIDD 256

// ---------- helpers ----------
__device__ __forceinline__ u16 f2bf(float f) {
  unsigned int u = __float_as_uint(f);
  u = u + 0x7FFFu + ((u >> 16) & 1u);   // RNE
  return (u16)(u >> 16);
}
__device__ __forceinline__ float bf2f(u16 h) {
  return __uint_as_float(((unsigned int)h) << 16);
}
__device__ __forceinline__ float gelu_f(float x) {
  return 0.5f * x * (1.0f + erff(x * 0.70710678118654752f));
}
__device__ __forceinline__ void gload_lds16(const u16* g, u16* l) {
  __builtin_amdgcn_global_load_lds((const __attribute__((address_space(1))) void*)g,
                                   (__attribute__((address_space(3))) void*)l, 16, 0, 0);
}

// ---------- K0: adjacency -> bitset rows (float4 loads + nibble LDS assembly) ----------
__global__ __launch_bounds__(256) void k_bitset(const float* __restrict__ A, u64* __restrict__ B1) {
  __shared__ unsigned char nib[4][1024];
  int wv = threadIdx.x >> 6, ln = threadIdx.x & 63;
  int row = blockIdx.x * 4 + wv;
  const float4* ar = (const float4*)(A + (size_t)row * NN);
#pragma unroll
  for (int it = 0; it < 16; ++it) {
    float4 v = ar[it * 64 + ln];
    unsigned n = (v.x != 0.f ? 1u : 0u) | (v.y != 0.f ? 2u : 0u) |
                 (v.z != 0.f ? 4u : 0u) | (v.w != 0.f ? 8u : 0u);
    nib[wv][it * 64 + ln] = (unsigned char)n;
  }
  __syncthreads();
  const u32* np4 = (const u32*)&nib[wv][ln * 16];
  u64 word = 0;
#pragma unroll
  for (int q = 0; q < 4; ++q) {
    u32 four = np4[q];
    u64 part = (u64)(four & 0xFu) | ((u64)((four >> 8) & 0xFu) << 4) |
               ((u64)((four >> 16) & 0xFu) << 8) | ((u64)((four >> 24) & 0xFu) << 12);
    word |= part << (16 * q);
  }
  B1[(size_t)row * 64 + ln] = word;
}

// ---------- boolean mat-power expansion: dst_row = OR_{m in src_row} base[m] ----------
#define MAXE 96
__global__ __launch_bounds__(256) void k_expand(const u64* __restrict__ src,
                                                const u64* __restrict__ base,
                                                u64* __restrict__ dst) {
  __shared__ int idxs[4][MAXE];
  __shared__ int cnts[4];
  int wv = threadIdx.x >> 6, ln = threadIdx.x & 63;
  int row = blockIdx.x * 4 + wv;
  if (ln == 0) cnts[wv] = 0;
  __syncthreads();
  u64 w = src[(size_t)row * 64 + ln];
  while (w) {
    int b = __builtin_ctzll(w);
    w &= w - 1;
    int p = atomicAdd(&cnts[wv], 1);
    if (p < MAXE) idxs[wv][p] = ln * 64 + b;
  }
  __syncthreads();
  int cnt = cnts[wv] < MAXE ? cnts[wv] : MAXE;
  u64 acc = 0;
  int i = 0;
  for (; i + 4 <= cnt; i += 4) {
    u64 a0 = base[(size_t)idxs[wv][i] * 64 + ln];
    u64 a1 = base[(size_t)idxs[wv][i + 1] * 64 + ln];
    u64 a2 = base[(size_t)idxs[wv][i + 2] * 64 + ln];
    u64 a3 = base[(size_t)idxs[wv][i + 3] * 64 + ln];
    acc |= a0 | a1 | a2 | a3;
  }
  for (; i < cnt; ++i) acc |= base[(size_t)idxs[wv][i] * 64 + ln];
  dst[(size_t)row * 64 + ln] = acc;
}

// ---------- fused prep: WsT, WlT (B-pattern) + X split (A-pattern) ----------
__global__ __launch_bounds__(256) void k_prep(const float* __restrict__ W0,
                                              const float* __restrict__ W1,
                                              const float* __restrict__ X,
                                              u16* __restrict__ d0,
                                              u16* __restrict__ d1,
                                              u16* __restrict__ dx) {
  int blk = blockIdx.x, t = threadIdx.x;
  if (blk < 512) {
    const float* W = blk < 256 ? W0 : W1;
    u16* dst = blk < 256 ? d0 : d1;
    int n = blk & 255;
    float x = W[(size_t)t * 256 + n];
    u16 hi = f2bf(x), lo = f2bf(x - bf2f(hi));
    size_t b = (size_t)n * 768 + t;
    dst[b] = hi; dst[b + 256] = hi; dst[b + 512] = lo;   // B-pattern
  } else {
    int rrow = blk - 512;
    float x = X[(size_t)rrow * 256 + t];
    u16 hi = f2bf(x), lo = f2bf(x - bf2f(hi));
    size_t b = (size_t)rrow * 768 + t;
    dx[b] = hi; dx[b + 256] = lo; dx[b + 512] = hi;      // A-pattern
  }
}

// ---------- sum 2 split-K partials then split (B-pattern hi,hi,lo) ----------
__global__ __launch_bounds__(256) void k_split_r2(const float* __restrict__ p,
                                                  u16* __restrict__ dst) {
  int rrow = blockIdx.x, c = threadIdx.x;
  size_t idx = (size_t)rrow * 256 + c;
  const size_t P = (size_t)NN * 256;
  float x = p[idx] + p[idx + P];
  u16 hi = f2bf(x);
  u16 lo = f2bf(x - bf2f(hi));
  size_t b = (size_t)rrow * 768 + c;
  dst[b] = hi;
  dst[b + 256] = hi;
  dst[b + 512] = lo;
}

// ---------- fused: Wh = sum 2 partials; s_i/s_j dots ----------
__global__ __launch_bounds__(256) void k_reduce2_sisj(const float* __restrict__ p,
                                                      const float* __restrict__ r,
                                                      float* __restrict__ Wh,
                                                      float* __restrict__ s) {
  int wv = threadIdx.x >> 6, ln = threadIdx.x & 63;
  int row = blockIdx.x * 4 + wv;
  const size_t P = (size_t)NN * 256;
  size_t idx = (size_t)row * 256 + ln * 4;
  float4 a = *(const float4*)&p[idx];
  float4 b = *(const float4*)&p[idx + P];
  float4 wh;
  wh.x = a.x + b.x; wh.y = a.y + b.y; wh.z = a.z + b.z; wh.w = a.w + b.w;
  *(float4*)&Wh[idx] = wh;
  const float4 ri = *(const float4*)&r[ln * 4];
  const float4 rj = *(const float4*)&r[256 + ln * 4];
  float pi = wh.x * ri.x + wh.y * ri.y + wh.z * ri.z + wh.w * ri.w;
  float pj = wh.x * rj.x + wh.y * rj.y + wh.z * rj.z + wh.w * rj.w;
  for (int o = 32; o; o >>= 1) { pi += __shfl_xor(pi, o); pj += __shfl_xor(pj, o); }
  if (ln == 0) { s[row] = pi; s[NN + row] = pj; }
}

// ---------- m97-style NT GEMM 128x128 with T2 XOR swizzle ----------
// Swizzle (rule #21): linear LDS dest; SOURCE k-offset pre-swizzled
// (skoff = ((lane&3)^(srow&3))*8); READ fk ^= (fr&3)<<3. 8-way -> 2-way (free).
__global__ __launch_bounds__(256) void gemm_nt(const u16* __restrict__ A,
                                               const u16* __restrict__ B,
                                               float* __restrict__ C,
                                               int M, int N, int K) {
  __shared__ __align__(16) u16 sA[128 * 32];
  __shared__ __align__(16) u16 sB[128 * 32];
  const int tid = threadIdx.x;
  const int wave = tid >> 6, lane = tid & 63;
  const int wr = wave >> 1, wc = wave & 1;

  int bx = blockIdx.x, by = blockIdx.y;
  {
    int nwg = gridDim.x * gridDim.y;
    if (gridDim.z == 1 && (nwg & 7) == 0) {
      int bid = by * gridDim.x + bx;
      int cpx = nwg >> 3;
      bid = (bid & 7) * cpx + (bid >> 3);
      bx = bid % gridDim.x;
      by = bid / gridDim.x;
    }
  }

  const int rowBase = by * 128;
  const int colBase = bx * 128;
  const int kchunk = K / gridDim.z;
  const int k0 = blockIdx.z * kchunk;
  float* Cp = C + (size_t)blockIdx.z * M * N;

  const int srow = lane >> 2;
  const int skoff = ((lane & 3) ^ (srow & 3)) * 8;   // source pre-swizzle
  const int fr = lane & 15;
  const int fk = ((lane >> 4) * 8) ^ ((fr & 3) << 3); // swizzled read slot

  f32x4 acc[4][4] = {};

  for (int kt = k0; kt < k0 + kchunk; kt += 32) {
    for (int c = wave; c < 8; c += 4) {
      const u16* ga = A + (size_t)(rowBase + c * 16 + srow) * K + kt + skoff;
      gload_lds16(ga, &sA[c * 512]);
      const u16* gb = B + (size_t)(colBase + c * 16 + srow) * K + kt + skoff;
      gload_lds16(gb, &sB[c * 512]);
    }
    __syncthreads();
    bf16x8 af[4], bfr[4];
#pragma unroll
    for (int m = 0; m < 4; ++m)
      af[m] = *(const bf16x8*)&sA[(wr * 64 + m * 16 + fr) * 32 + fk];
#pragma unroll
    for (int n = 0; n < 4; ++n)
      bfr[n] = *(const bf16x8*)&sB[(wc * 64 + n * 16 + fr) * 32 + fk];
#pragma unroll
    for (int m = 0; m < 4; ++m)
#pragma unroll
      for (int n = 0; n < 4; ++n)
        acc[m][n] = __builtin_amdgcn_mfma_f32_16x16x32_bf16(af[m], bfr[n], acc[m][n], 0, 0, 0);
    __syncthreads();
  }
#pragma unroll
  for (int m = 0; m < 4; ++m)
#pragma unroll
    for (int n = 0; n < 4; ++n) {
      int r0 = rowBase + wr * 64 + m * 16 + (lane >> 4) * 4;
      int c0 = colBase + wc * 64 + n * 16 + fr;
#pragma unroll
      for (int r = 0; r < 4; ++r)
        Cp[(size_t)(r0 + r) * N + c0] = acc[m][n][r];
    }
}

// ---------- 64x64-tile NT GEMM (same swizzle) ----------
__global__ __launch_bounds__(256) void gemm64_nt(const u16* __restrict__ A,
                                                 const u16* __restrict__ B,
                                                 float* __restrict__ C,
                                                 int M, int N, int K) {
  __shared__ __align__(16) u16 sA[64 * 32];
  __shared__ __align__(16) u16 sB[64 * 32];
  const int tid = threadIdx.x;
  const int wave = tid >> 6, lane = tid & 63;
  const int wr = wave >> 1, wc = wave & 1;
  const int rowBase = blockIdx.y * 64;
  const int colBase = blockIdx.x * 64;
  const int kchunk = K / gridDim.z;
  const int k0 = blockIdx.z * kchunk;
  float* Cp = C + (size_t)blockIdx.z * M * N;

  const int srow = lane >> 2;
  const int skoff = ((lane & 3) ^ (srow & 3)) * 8;
  const int fr = lane & 15;
  const int fk = ((lane >> 4) * 8) ^ ((fr & 3) << 3);

  f32x4 acc[2][2] = {};

  for (int kt = k0; kt < k0 + kchunk; kt += 32) {
    const u16* ga = A + (size_t)(rowBase + wave * 16 + srow) * K + kt + skoff;
    gload_lds16(ga, &sA[wave * 512]);
    const u16* gb = B + (size_t)(colBase + wave * 16 + srow) * K + kt + skoff;
    gload_lds16(gb, &sB[wave * 512]);
    __syncthreads();
    bf16x8 af[2], bfr[2];
#pragma unroll
    for (int m = 0; m < 2; ++m)
      af[m] = *(const bf16x8*)&sA[(wr * 32 + m * 16 + fr) * 32 + fk];
#pragma unroll
    for (int n = 0; n < 2; ++n)
      bfr[n] = *(const bf16x8*)&sB[(wc * 32 + n * 16 + fr) * 32 + fk];
#pragma unroll
    for (int m = 0; m < 2; ++m)
#pragma unroll
      for (int n = 0; n < 2; ++n)
        acc[m][n] = __builtin_amdgcn_mfma_f32_16x16x32_bf16(af[m], bfr[n], acc[m][n], 0, 0, 0);
    __syncthreads();
  }
#pragma unroll
  for (int m = 0; m < 2; ++m)
#pragma unroll
    for (int n = 0; n < 2; ++n) {
      int r0 = rowBase + wr * 32 + m * 16 + (lane >> 4) * 4;
      int c0 = colBase + wc * 32 + n * 16 + fr;
#pragma unroll
      for (int r = 0; r < 4; ++r)
        Cp[(size_t)(r0 + r) * N + c0] = acc[m][n][r];
    }
}

// ---------- phase-1 sparse GAT attention + gelu (wave per row) ----------
#define MAXD 128
__global__ __launch_bounds__(256) void k_attn1(const u64* __restrict__ B1,
                                               const float* __restrict__ s,
                                               const float* __restrict__ Wh,
                                               float* __restrict__ h) {
  __shared__ int idxs[4][MAXD];
  __shared__ float ww[4][MAXD];
  __shared__ int cnts[4];
  int wv = threadIdx.x >> 6, ln = threadIdx.x & 63;
  int row = blockIdx.x * 4 + wv;
  if (ln == 0) cnts[wv] = 0;
  __syncthreads();
  u64 w = B1[(size_t)row * 64 + ln];
  while (w) {
    int b = __builtin_ctzll(w);
    w &= w - 1;
    int p = atomicAdd(&cnts[wv], 1);
    if (p < MAXD) idxs[wv][p] = ln * 64 + b;
  }
  __syncthreads();
  int cnt = cnts[wv] < MAXD ? cnts[wv] : MAXD;
  float si = s[row];
  for (int i = ln; i < cnt; i += 64) {
    float v = si + s[NN + idxs[wv][i]];
    ww[wv][i] = v > 0.f ? v : 0.2f * v;
  }
  __syncthreads();
  float mx = -1e30f;
  for (int i = ln; i < cnt; i += 64) mx = fmaxf(mx, ww[wv][i]);
  for (int o = 32; o; o >>= 1) mx = fmaxf(mx, __shfl_xor(mx, o));
  float sm = 0.f;
  for (int i = ln; i < cnt; i += 64) sm += __expf(ww[wv][i] - mx);
  for (int o = 32; o; o >>= 1) sm += __shfl_xor(sm, o);
  float inv = 1.0f / sm;
  for (int i = ln; i < cnt; i += 64) ww[wv][i] = __expf(ww[wv][i] - mx) * inv;
  __syncthreads();
  float a0 = 0, a1 = 0, a2 = 0, a3 = 0;
  for (int t = 0; t < cnt; ++t) {
    float wgt = ww[wv][t];
    const float4 v = *(const float4*)&Wh[(size_t)idxs[wv][t] * 256 + ln * 4];
    a0 = fmaf(wgt, v.x, a0); a1 = fmaf(wgt, v.y, a1);
    a2 = fmaf(wgt, v.z, a2); a3 = fmaf(wgt, v.w, a3);
  }
  float4 o4;
  o4.x = gelu_f(a0); o4.y = gelu_f(a1); o4.z = gelu_f(a2); o4.w = gelu_f(a3);
  *(float4*)&h[(size_t)row * 256 + ln * 4] = o4;
}

// ---------- fused: h -> hsp (A-pattern split) + hT (bf16 transpose) ----------
__global__ __launch_bounds__(256) void k_splitH_T(const float* __restrict__ h,
                                                  u16* __restrict__ hsp,
                                                  u16* __restrict__ hT) {
  __shared__ u16 tile[64][260];   // pad: 520B row stride -> banks spread
  int t = threadIdx.x;
  int row0 = blockIdx.x * 64;
#pragma unroll
  for (int it = 0; it < 16; ++it) {
    int idx = it * 256 + t;
    int rr = idx >> 6;
    int c4 = (idx & 63) * 4;
    float4 v = *(const float4*)&h[(size_t)(row0 + rr) * 256 + c4];
    u16 h0 = f2bf(v.x), h1 = f2bf(v.y), h2 = f2bf(v.z), h3 = f2bf(v.w);
    u16 l0 = f2bf(v.x - bf2f(h0)), l1 = f2bf(v.y - bf2f(h1));
    u16 l2 = f2bf(v.z - bf2f(h2)), l3 = f2bf(v.w - bf2f(h3));
    ushort4 hv = {h0, h1, h2, h3}, lv = {l0, l1, l2, l3};
    size_t b = (size_t)(row0 + rr) * 768 + c4;
    *(ushort4*)&hsp[b] = hv;          // hi
    *(ushort4*)&hsp[b + 256] = lv;    // lo  (A-pattern: hi,lo,hi)
    *(ushort4*)&hsp[b + 512] = hv;    // hi
    *(ushort4*)&tile[rr][c4] = hv;    // 520B stride, 8B-aligned
  }
  __syncthreads();
#pragma unroll
  for (int it = 0; it < 64; ++it) {
    int col = it * 4 + (t >> 6);
    hT[(size_t)col * NN + row0 + (t & 63)] = tile[t & 63][col];
  }
}

// ---------- combined 3-hop softmax weights: Wc = w1+w2+w3 ----------
__global__ __launch_bounds__(256) void k_wc(const float* __restrict__ scores,
                                            const u64* __restrict__ B1,
                                            const u64* __restrict__ B2,
                                            const u64* __restrict__ B3,
                                            u16* __restrict__ Wc) {
  __shared__ u64 sm3[64];
  __shared__ float rmax[4], rsum[4];
  const int t = threadIdx.x;
  const int wv = t >> 6, ln = t & 63;
  const int row = blockIdx.x;
  const size_t rbase = (size_t)row * NN;

  if (t < 64) sm3[t] = B3[(size_t)row * 64 + t];
  f32x4 v[4];
  const f32x4* sp = (const f32x4*)(scores + rbase);
#pragma unroll
  for (int g = 0; g < 4; ++g) v[g] = sp[g * 256 + t];
  u64 w2 = 0, w1 = 0;
  if (wv == 0) {
    w2 = B2[(size_t)row * 64 + ln];
    w1 = B1[(size_t)row * 64 + ln];
  }
  __syncthreads();

  const int wi = t >> 4;
  const int sb = (t & 15) * 4;
  u32 nib[4];
  float mx3 = -3e38f;
#pragma unroll
  for (int g = 0; g < 4; ++g) {
    u64 wrd = sm3[g * 16 + wi];
    u32 half = (sb < 32) ? (u32)wrd : (u32)(wrd >> 32);
    nib[g] = (half >> (sb & 31)) & 0xFu;
#pragma unroll
    for (int j = 0; j < 4; ++j)
      if (nib[g] & (1u << j)) mx3 = fmaxf(mx3, v[g][j]);
  }
  for (int o = 32; o; o >>= 1) mx3 = fmaxf(mx3, __shfl_xor(mx3, o));
  if (ln == 0) rmax[wv] = mx3;

  float mx2 = -3e38f, mx1 = -3e38f;
  if (wv == 0) {
    u64 w = w2;
    while (w) {
      int b = __builtin_ctzll(w); w &= w - 1;
      float sc = scores[rbase + ln * 64 + b];
      mx2 = fmaxf(mx2, sc);
      if (w1 & (1ull << b)) mx1 = fmaxf(mx1, sc);
    }
    for (int o = 32; o; o >>= 1) {
      mx2 = fmaxf(mx2, __shfl_xor(mx2, o));
      mx1 = fmaxf(mx1, __shfl_xor(mx1, o));
    }
  }
  __syncthreads();
  mx3 = fmaxf(fmaxf(rmax[0], rmax[1]), fmaxf(rmax[2], rmax[3]));

  float s3 = 0.f;
#pragma unroll
  for (int g = 0; g < 4; ++g)
#pragma unroll
    for (int j = 0; j < 4; ++j) {
      float e = __expf(v[g][j] - mx3);
      e = (nib[g] & (1u << j)) ? e : 0.f;
      v[g][j] = e;
      s3 += e;
    }
  for (int o = 32; o; o >>= 1) s3 += __shfl_xor(s3, o);
  if (ln == 0) rsum[wv] = s3;

  float s2 = 1.f, s1 = 1.f;
  if (wv == 0) {
    float s2p = 0.f, s1p = 0.f;
    u64 w = w2;
    while (w) {
      int b = __builtin_ctzll(w); w &= w - 1;
      float sc = scores[rbase + ln * 64 + b];
      s2p += __expf(sc - mx2);
      if (w1 & (1ull << b)) s1p += __expf(sc - mx1);
    }
    for (int o = 32; o; o >>= 1) {
      s2p += __shfl_xor(s2p, o);
      s1p += __shfl_xor(s1p, o);
    }
    s2 = s2p; s1 = s1p;
  }
  __syncthreads();
  s3 = rsum[0] + rsum[1] + rsum[2] + rsum[3];
  float inv3 = 1.0f / s3;

#pragma unroll
  for (int g = 0; g < 4; ++g) {
    u16 o0 = f2bf(v[g][0] * inv3), o1 = f2bf(v[g][1] * inv3);
    u16 o2 = f2bf(v[g][2] * inv3), o3 = f2bf(v[g][3] * inv3);
    uint2 pk;
    pk.x = (u32)o0 | ((u32)o1 << 16);
    pk.y = (u32)o2 | ((u32)o3 << 16);
    *(uint2*)&Wc[rbase + (size_t)g * 1024 + t * 4] = pk;
  }
  __syncthreads();

  if (wv == 0) {
    float inv2 = 1.0f / s2, inv1 = 1.0f / s1;
    u64 w = w2;
    while (w) {
      int b = __builtin_ctzll(w); w &= w - 1;
      int c = ln * 64 + b;
      float sc = scores[rbase + c];
      float wgt = __expf(sc - mx3) * inv3 + __expf(sc - mx2) * inv2;
      if (w1 & (1ull << b)) wgt += __expf(sc - mx1) * inv1;
      Wc[rbase + c] = f2bf(wgt);
    }
  }
}

// ---------- final: out = (h + sum tmp_z) @ W_out + b_out ----------
__global__ __launch_bounds__(128) void k_final(const float* __restrict__ h,
                                               const float* __restrict__ tmp,
                                               const float* __restrict__ Wout,
                                               const float* __restrict__ bout,
                                               float* __restrict__ out) {
  __shared__ float rrow[8][256];
  int t = threadIdx.x;
  int row0 = blockIdx.x * 8;
  const size_t P = (size_t)NN * 256;
  for (int i = t; i < 8 * 256; i += 128) {
    int rr = i >> 8, k = i & 255;
    size_t idx = (size_t)(row0 + rr) * 256 + k;
    rrow[rr][k] = h[idx] + tmp[idx] + tmp[idx + P] + tmp[idx + 2 * P] + tmp[idx + 3 * P];
  }
  __syncthreads();
  float b = bout[t];
  float acc[8];
#pragma unroll
  for (int i = 0; i < 8; ++i) acc[i] = b;
  for (int k = 0; k < 256; ++k) {
    float w = Wout[k * 128 + t];
#pragma unroll
    for (int i = 0; i < 8; ++i) acc[i] = fmaf(rrow[i][k], w, acc[i]);
  }
#pragma unroll
  for (int i = 0; i < 8; ++i) out[(size_t)(row0 + i) * 128 + t] = acc[i];
}

// ---------- host ----------
extern "C" void kernel_launch(void* const* d_in, const int* in_sizes, int n_in,
                              void* d_out, int out_size, void* d_ws, size_t ws_size,
                              hipStream_t stream) {
  const float* X    = (const float*)d_in[0];
  const float* A    = (const float*)d_in[1];
  const float* W_s  = (const float*)d_in[2];
  const float* r    = (const float*)d_in[3];
  const float* W_l  = (const float*)d_in[4];
  const float* Wout = (const float*)d_in[5];
  const float* bout = (const float*)d_in[6];
  float* out = (float*)d_out;

  char* wp = (char*)d_ws;
  auto take = [&](size_t n) { char* p = wp; wp += (n + 255) & ~(size_t)255; return p; };
  u64* B1     = (u64*)take((size_t)NN * 64 * 8);      // 2 MB
  u64* B2     = (u64*)take((size_t)NN * 64 * 8);      // 2 MB
  u64* B3     = (u64*)take((size_t)NN * 64 * 8);      // 2 MB
  float* Wh   = (float*)take((size_t)NN * 256 * 4);   // 4 MB
  float* sv   = (float*)take((size_t)2 * NN * 4);     // 32 KB
  float* h    = (float*)take((size_t)NN * 256 * 4);   // 4 MB
  u16* hT     = (u16*)take((size_t)256 * NN * 2);     // 2 MB
  u16* hsp    = (u16*)take((size_t)NN * 768 * 2);     // 6 MB
  u16* Wasp   = (u16*)take((size_t)NN * 768 * 2);     // 6 MB
  u16* Xsp    = (u16*)take((size_t)NN * 768 * 2);     // 6 MB
  u16* WsT    = (u16*)take((size_t)256 * 768 * 2);
  u16* WlT    = (u16*)take((size_t)256 * 768 * 2);
  float* scores = (float*)take((size_t)NN * NN * 4);  // 64 MB; front reused:
  float* Whp  = scores;                               //   2x4MB Wh partials (dead pre-scores)
  float* Wap  = scores + (size_t)2 * NN * 256;        //   2x4MB Wa partials (dead pre-scores)
  float* tmp  = scores;                               //   4x4MB Wc@h partials (post-k_wc)
  u16* Wc     = (u16*)take((size_t)NN * NN * 2);      // 32 MB
  (void)n_in; (void)in_sizes; (void)out_size; (void)ws_size;

  // masks
  k_bitset<<<NN / 4, 256, 0, stream>>>(A, B1);
  k_expand<<<NN / 4, 256, 0, stream>>>(B1, B1, B2);
  k_expand<<<NN / 4, 256, 0, stream>>>(B1, B2, B3);   // B3 = B1*B2
  // fused weight+X prep
  k_prep<<<512 + NN, 256, 0, stream>>>(W_s, W_l, X, WsT, WlT, Xsp);
  // Wh = X @ W_s (64-tile, split-K2 -> fused reduce+sisj)
  gemm64_nt<<<dim3(4, 64, 2), 256, 0, stream>>>(Xsp, WsT, Whp, NN, 256, 768);
  k_reduce2_sisj<<<NN / 4, 256, 0, stream>>>(Whp, r, Wh, sv);
  k_attn1<<<NN / 4, 256, 0, stream>>>(B1, sv, Wh, h);
  // fused h split + transpose
  k_splitH_T<<<64, 256, 0, stream>>>(h, hsp, hT);
  // Wa = h @ W_l (64-tile, split-K2; reduce fused into split)
  gemm64_nt<<<dim3(4, 64, 2), 256, 0, stream>>>(hsp, WlT, Wap, NN, 256, 768);
  k_split_r2<<<NN, 256, 0, stream>>>(Wap, Wasp);
  // scores = h @ Wa^T  (split-bf16, near-f32)
  gemm_nt<<<dim3(32, 32, 1), 256, 0, stream>>>(hsp, Wasp, scores, NN, NN, 768);
  // combined 3-hop softmax weights
  k_wc<<<NN, 256, 0, stream>>>(scores, B1, B2, B3, Wc);
  // tmp = Wc @ h   (64-tile, split-K=4 over K=4096)
  gemm64_nt<<<dim3(4, 64, 4), 256, 0, stream>>>(Wc, hT, tmp, NN, 256, NN);
  // out = (h + tmp) @ W_out + b_out
  k_final<<<NN / 8, 128, 0, stream>>>(h, tmp, Wout, bout, out);
}